// Round 5
// baseline (586.327 us; speedup 1.0000x reference)
//
#include <hip/hip_runtime.h>
#include <hip/hip_bf16.h>
#include <math.h>

typedef __hip_bfloat16 bf16;
typedef short short8 __attribute__((ext_vector_type(8)));
typedef short short4v __attribute__((ext_vector_type(4)));
typedef float f32x4 __attribute__((ext_vector_type(4)));

#define B_ 8
#define L_ 2048
#define DM 1024
#define DI 2048
#define NH 32
#define HD 64
#define DS 128
#define NWPAD 4480     // padded W_in rows: 4384 -> 35*128 (128-tile inproj GEMM)
#define XW 2432        // xBCdt width: 2336 -> 19*128
#define CONVD 2304
#define NC 32
#define CK 64
#define HG 16          // heads per SSD group (states buffer granularity)
#define NGRP (NH / HG)
#define BL (B_ * L_)

// ---------------- MFMA via inline asm ----------------
static __device__ __forceinline__ f32x4 mfma_bf16(short8 a, short8 b, f32x4 c) {
  asm("v_mfma_f32_16x16x32_bf16 %0, %1, %2, %0" : "+v"(c) : "v"(a), "v"(b));
  return c;
}

static __device__ __forceinline__ void gload16(const bf16* g, bf16* l) {
  __builtin_amdgcn_global_load_lds((const __attribute__((address_space(1))) void*)g,
                                   (__attribute__((address_space(3))) void*)l, 16, 0, 0);
}

static __device__ __forceinline__ short bf2s(float f) {
  bf16 b = __float2bfloat16(f);
  return *reinterpret_cast<short*>(&b);
}

static __device__ __forceinline__ float s2f(short s) {
  unsigned int u = ((unsigned int)(unsigned short)s) << 16;
  return __uint_as_float(u);
}

// ---------------- weight conversion (merged, index-verified) ----------------
__global__ void cvt_k(const float* __restrict__ Wi, const float* __restrict__ Wo,
                      bf16* __restrict__ Wib, bf16* __restrict__ Wob) {
  size_t i = (size_t)blockIdx.x * 256 + threadIdx.x;
  const size_t NWI = (size_t)NWPAD * DM;          // 4587520
  if (i < NWI) {
    float v = (i < (size_t)4384 * 1024) ? Wi[i] : 0.f;   // zero-pad rows 4384..4479
    Wib[i] = __float2bfloat16(v);
  } else {
    size_t j = i - NWI;                            // < DM*DI
    Wob[j] = __float2bfloat16(Wo[j]);
  }
}

// ---------------- LayerNorm -> bf16 (float4-vectorized) ----------------
__global__ void ln_k(const float* __restrict__ x, const float* __restrict__ w,
                     const float* __restrict__ bz, bf16* __restrict__ xn) {
  __shared__ float sm1[4], sm2[4];
  int row = blockIdx.x, tid = threadIdx.x;
  int d0 = tid * 4;
  const float* xr = x + (size_t)row * DM;
  float4 v4 = *(const float4*)&xr[d0];
  float v[4] = {v4.x, v4.y, v4.z, v4.w};
  float s = v[0] + v[1] + v[2] + v[3];
#pragma unroll
  for (int o = 32; o > 0; o >>= 1) s += __shfl_down(s, o, 64);
  if ((tid & 63) == 0) sm1[tid >> 6] = s;
  __syncthreads();
  float mean = (sm1[0] + sm1[1] + sm1[2] + sm1[3]) * (1.f / DM);
  float q = 0.f;
#pragma unroll
  for (int i = 0; i < 4; i++) { float d = v[i] - mean; q += d * d; }
#pragma unroll
  for (int o = 32; o > 0; o >>= 1) q += __shfl_down(q, o, 64);
  if ((tid & 63) == 0) sm2[tid >> 6] = q;
  __syncthreads();
  float rstd = rsqrtf((sm2[0] + sm2[1] + sm2[2] + sm2[3]) * (1.f / DM) + 1e-5f);
  float4 w4 = *(const float4*)&w[d0];
  float4 b4 = *(const float4*)&bz[d0];
  short4v o4;
  o4[0] = bf2s((v[0] - mean) * rstd * w4.x + b4.x);
  o4[1] = bf2s((v[1] - mean) * rstd * w4.y + b4.y);
  o4[2] = bf2s((v[2] - mean) * rstd * w4.z + b4.z);
  o4[3] = bf2s((v[3] - mean) * rstd * w4.w + b4.w);
  *(short4v*)&xn[(size_t)row * DM + d0] = o4;
}

// ============ 128x128 2-phase GEMM core (proven 865 TF) ============
// COLSWZ=1: each XCD owns a contiguous bx-strip (by cycles fast) -> B-panel
// slice (~1.1 MB) stays L2-resident per XCD; A streams from L3. For inproj
// (B-panel 9 MB > 4 MB L2), this shortens the per-K-step stage latency.
// COLSWZ=0: proven row-mode (gemm_out: B-panel 4 MB ~ L2-fits already).
#define GEMM_PROLOGUE(Kdim, COLSWZ)                                             \
  const int tid = threadIdx.x;                                                  \
  const int lane = tid & 63;                                                    \
  const int wave = tid >> 6;                                                    \
  int nwg = gridDim.x * gridDim.y;                                              \
  int id = blockIdx.y * gridDim.x + blockIdx.x;                                 \
  int bx = blockIdx.x, by = blockIdx.y;                                         \
  if ((nwg & 7) == 0) {                                                         \
    int swz = (id & 7) * (nwg >> 3) + (id >> 3);                                \
    if (COLSWZ) {                                                               \
      by = swz % gridDim.y;                                                     \
      bx = swz / gridDim.y;                                                     \
    } else {                                                                    \
      bx = swz % gridDim.x;                                                     \
      by = swz / gridDim.x;                                                     \
    }                                                                           \
  }                                                                             \
  const int m0 = by * 128, n0 = bx * 128;                                       \
  const int wm = (wave >> 1) * 64, wn = (wave & 1) * 64;                        \
  const int srow = tid >> 3;                                                    \
  const int schunk = tid & 7;                                                   \
  f32x4 acc[4][4];                                                              \
  _Pragma("unroll")                                                             \
  for (int i = 0; i < 4; i++)                                                   \
    _Pragma("unroll")                                                           \
    for (int j = 0; j < 4; j++) acc[i][j] = (f32x4){0.f, 0.f, 0.f, 0.f};        \
  for (int kt = 0; kt < (Kdim); kt += 64) {                                     \
    __syncthreads();                                                            \
    _Pragma("unroll")                                                           \
    for (int is = 0; is < 4; is++) {                                            \
      int row = is * 32 + srow;                                                 \
      int gcol = (schunk ^ (row & 7)) << 3;                                     \
      const bf16* ga = A + (size_t)(m0 + row) * (Kdim) + kt + gcol;             \
      const bf16* gb = Bw + (size_t)(n0 + row) * (Kdim) + kt + gcol;            \
      bf16* la = &As[(is * 32 + wave * 8) * 64];                                \
      bf16* lb = &Bs[(is * 32 + wave * 8) * 64];                                \
      gload16(ga, la);                                                          \
      gload16(gb, lb);                                                          \
    }                                                                           \
    __syncthreads();                                                            \
    _Pragma("unroll")                                                           \
    for (int kk = 0; kk < 2; kk++) {                                            \
      short8 af[4], bfr[4];                                                     \
      int mrow = lane & 15;                                                     \
      int kch = kk * 4 + (lane >> 4);                                           \
      _Pragma("unroll")                                                         \
      for (int mi = 0; mi < 4; mi++) {                                          \
        int r = wm + mi * 16 + mrow;                                            \
        af[mi] = *(const short8*)&As[r * 64 + ((kch ^ (r & 7)) << 3)];          \
      }                                                                         \
      _Pragma("unroll")                                                         \
      for (int ni = 0; ni < 4; ni++) {                                          \
        int r = wn + ni * 16 + mrow;                                            \
        bfr[ni] = *(const short8*)&Bs[r * 64 + ((kch ^ (r & 7)) << 3)];         \
      }                                                                         \
      _Pragma("unroll")                                                         \
      for (int mi = 0; mi < 4; mi++)                                            \
        _Pragma("unroll")                                                       \
        for (int ni = 0; ni < 4; ni++)                                          \
          acc[mi][ni] = mfma_bf16(af[mi], bfr[ni], acc[mi][ni]);                \
    }                                                                           \
  }                                                                             \
  asm volatile("s_nop 7\n\ts_nop 7" ::);                                        \
  const int orow = (lane >> 4) << 2;                                            \
  const int ocol = lane & 15;

// ---------------- merged in-proj GEMM: z -> zb, xBCdt -> xb (128², COLSWZ) ------
__global__ __launch_bounds__(256) void gemm_inproj_k(
    const bf16* __restrict__ A, const bf16* __restrict__ Bw,
    bf16* __restrict__ zb, bf16* __restrict__ xb) {
  __shared__ bf16 As[128 * 64];
  __shared__ bf16 Bs[128 * 64];
  GEMM_PROLOGUE(DM, 1)
#pragma unroll
  for (int mi = 0; mi < 4; mi++) {
#pragma unroll
    for (int ni = 0; ni < 4; ni++) {
      int rbase = m0 + wm + mi * 16 + orow;
      int cc = n0 + wn + ni * 16 + ocol;
#pragma unroll
      for (int r = 0; r < 4; r++) {
        bf16 v = __float2bfloat16(acc[mi][ni][r]);
        if (cc < DI) zb[(size_t)(rbase + r) * DI + cc] = v;
        else         xb[(size_t)(rbase + r) * XW + (cc - DI)] = v;
      }
    }
  }
}

// ---------------- out-proj GEMM: f32 out + residual (128², proven) ----------------
__global__ __launch_bounds__(256) void gemm_out_k(
    const bf16* __restrict__ A, const bf16* __restrict__ Bw,
    float* __restrict__ C, const float* __restrict__ resid) {
  __shared__ bf16 As[128 * 64];
  __shared__ bf16 Bs[128 * 64];
  GEMM_PROLOGUE(DI, 0)
#pragma unroll
  for (int mi = 0; mi < 4; mi++) {
#pragma unroll
    for (int ni = 0; ni < 4; ni++) {
      int rbase = m0 + wm + mi * 16 + orow;
      int cc = n0 + wn + ni * 16 + ocol;
#pragma unroll
      for (int r = 0; r < 4; r++) {
        size_t idx = (size_t)(rbase + r) * DM + cc;
        C[idx] = acc[mi][ni][r] + resid[idx];
      }
    }
  }
}

// ---------------- causal depthwise conv4 + SiLU, split into xs/B/C -------------
__global__ void conv_k(const bf16* __restrict__ xbc, const float* __restrict__ conv_w,
                       const float* __restrict__ conv_b, bf16* __restrict__ xsb,
                       bf16* __restrict__ Bb, bf16* __restrict__ Cb) {
  int c = blockIdx.x * 256 + threadIdx.x;   // 0..2303
  int lbase = blockIdx.y * 16;
  int b = blockIdx.z;
  float4 w = ((const float4*)conv_w)[c];
  float bias = conv_b[c];
  const bf16* xp = xbc + (size_t)b * L_ * XW + c;
  float h0 = 0.f, h1 = 0.f, h2 = 0.f;
  if (lbase > 0) {
    h0 = __bfloat162float(xp[(size_t)(lbase - 3) * XW]);
    h1 = __bfloat162float(xp[(size_t)(lbase - 2) * XW]);
    h2 = __bfloat162float(xp[(size_t)(lbase - 1) * XW]);
  }
  for (int t = 0; t < 16; t++) {
    int l = lbase + t;
    float x3 = __bfloat162float(xp[(size_t)l * XW]);
    float v = bias + w.x * h0 + w.y * h1 + w.z * h2 + w.w * x3;
    v = v / (1.f + __expf(-v));
    bf16 o = __float2bfloat16(v);
    size_t rl = (size_t)b * L_ + l;
    if (c < DI)           xsb[rl * DI + c] = o;
    else if (c < DI + DS) Bb[rl * DS + (c - DI)] = o;
    else                  Cb[rl * DS + (c - DI - DS)] = o;
    h0 = h1; h1 = h2; h2 = x3;
  }
}

// ---------------- dt: softplus + A*dt (fp32), layout [h][b*l] ----------------
__global__ void dt_k(const bf16* __restrict__ xbc, const float* __restrict__ dt_bias,
                     const float* __restrict__ A_log, float* __restrict__ dtsp,
                     float* __restrict__ dta) {
  size_t i = (size_t)blockIdx.x * 256 + threadIdx.x;   // h-major: h = i>>14
  int h = (int)(i >> 14);
  size_t row = i & 16383;
  float raw = __bfloat162float(xbc[row * XW + CONVD + h]) + dt_bias[h];
  float sp = (raw > 20.f) ? raw : log1pf(__expf(raw));
  dtsp[i] = sp;
  dta[i] = -__expf(A_log[h]) * sp;
}

// ---------------- chunk_g_k: per (b,c, 8-head subgroup) ----------------
// Stage B/C once, compute G = C.B^T ONCE (head-independent, kept in registers),
// then loop 8 heads reusing the verified per-head fragment code.
__global__ __launch_bounds__(256) void chunk_g_k(
    const bf16* __restrict__ xsb, const bf16* __restrict__ Bb, const bf16* __restrict__ Cb,
    const float* __restrict__ dtsp, const float* __restrict__ dta,
    const float* __restrict__ Dv, int hbase,
    bf16* __restrict__ Y, bf16* __restrict__ states, float* __restrict__ cs63) {
  __shared__ __align__(16) bf16 Bs[64][136];   // B row-major (G + Btw), live whole kernel
  __shared__ __align__(16) bf16 Cs[64][136];   // C row-major (G)
  __shared__ __align__(16) bf16 Btw[128][72];  // B^T * w[l] (per head)
  __shared__ __align__(16) bf16 Xt[64][72];    // X^T (per head)
  __shared__ __align__(16) bf16 Sb[64][72];    // scores (per head)
  __shared__ float cs[64];
  __shared__ float wts[64];
  __shared__ float dts[64];

  int hgsub = blockIdx.x, c = blockIdx.y, b = blockIdx.z;
  int tid = threadIdx.x;
  int lane = tid & 63, wid = tid >> 6;
  size_t l0 = (size_t)b * L_ + (size_t)c * CK;

  // ---- stage Bs, Cs once ----
  for (int i = tid; i < 64 * 16; i += 256) {
    int r = i >> 4, n8 = (i & 15) << 3;
    *(short8*)&Bs[r][n8] = *(const short8*)&Bb[(l0 + r) * DS + n8];
    *(short8*)&Cs[r][n8] = *(const short8*)&Cb[(l0 + r) * DS + n8];
  }
  __syncthreads();

  // ---- G = C·B^T once (K=128): wave wid -> s-tile wid, 4 l-tiles ----
  f32x4 accg[4];
#pragma unroll
  for (int i = 0; i < 4; i++) accg[i] = (f32x4){0.f, 0.f, 0.f, 0.f};
  {
    int rb = wid * 16 + (lane & 15);
    int c0 = (lane >> 4) * 8;
#pragma unroll
    for (int kk = 0; kk < 4; kk++) {
      int kc = c0 + kk * 32;
      short8 bfrag = *(const short8*)&Bs[rb][kc];
#pragma unroll
      for (int lt = 0; lt < 4; lt++) {
        short8 afrag = *(const short8*)&Cs[lt * 16 + (lane & 15)][kc];
        accg[lt] = mfma_bf16(afrag, bfrag, accg[lt]);
      }
    }
  }
  asm volatile("s_nop 7\n\ts_nop 7" ::);

  for (int hh = 0; hh < 8; hh++) {
    int hl = hgsub * 8 + hh;         // local index within HG=16 group
    int h = hbase + hl;
    __syncthreads();                 // prior head's readers of Xt/Btw/Sb done

    // ---- stage Xt via gather-transpose ----
    {
      const bf16* xp = xsb + l0 * DI + h * HD + lane;
      for (int oct = wid; oct < 8; oct += 4) {
        int lb = oct * 8;
        short8 v;
#pragma unroll
        for (int j = 0; j < 8; j++)
          v[j] = *(const short*)&xp[(size_t)(lb + j) * DI];
        *(short8*)&Xt[lane][lb] = v;
      }
    }
    if (tid < 64) {
      dts[tid] = dtsp[(size_t)h * BL + l0 + tid];
      wts[tid] = dta[(size_t)h * BL + l0 + tid];
    }
    __syncthreads();
    // ---- wave-parallel inclusive prefix scan (wave 0) ----
    if (tid < 64) {
      float a = wts[tid];
#pragma unroll
      for (int o = 1; o < 64; o <<= 1) {
        float t = __shfl_up(a, o, 64);
        if (lane >= o) a += t;
      }
      cs[tid] = a;
      float tot = __shfl(a, 63, 64);
      if (tid == 63) cs63[((size_t)b * NH + h) * NC + c] = a;
      wts[tid] = __expf(tot - a) * dts[tid];
    }
    __syncthreads();

    // ---- Btw[n][l] = B[l][n]*w[l] gather (reads Bs + wts) ----
    for (int u = wid; u < 16; u += 4) {
      int nh = u & 1, oct = u >> 1;
      int n = nh * 64 + lane;
      int lb = oct * 8;
      short8 v;
#pragma unroll
      for (int j = 0; j < 8; j++)
        v[j] = bf2s(__bfloat162float(Bs[lb + j][n]) * wts[lb + j]);
      *(short8*)&Btw[n][lb] = v;
    }
    // ---- scores from register accg ----
    {
      int s = wid * 16 + (lane & 15);
      float css = cs[s], dtss = dts[s];
#pragma unroll
      for (int lt = 0; lt < 4; lt++) {
#pragma unroll
        for (int r = 0; r < 4; r++) {
          int l = lt * 16 + ((lane >> 4) << 2) + r;
          float v = (s <= l) ? accg[lt][r] * __expf(cs[l] - css) * dtss : 0.f;
          Sb[l][s] = __float2bfloat16(v);
        }
      }
    }
    __syncthreads();   // Sb + Btw ready

    // ---- Y = Sb·Xt (K=64): wave wid -> p-tile wid ----
    f32x4 accy[4];
#pragma unroll
    for (int i = 0; i < 4; i++) accy[i] = (f32x4){0.f, 0.f, 0.f, 0.f};
    {
      int prow = wid * 16 + (lane & 15);
      int c0 = (lane >> 4) * 8;
#pragma unroll
      for (int kk = 0; kk < 2; kk++) {
        int kc = c0 + kk * 32;
        short8 xfrag = *(const short8*)&Xt[prow][kc];
#pragma unroll
        for (int lt = 0; lt < 4; lt++) {
          short8 sfrag = *(const short8*)&Sb[lt * 16 + (lane & 15)][kc];
          accy[lt] = mfma_bf16(sfrag, xfrag, accy[lt]);
        }
      }
    }
    // ---- states = Xw^T·B (K=64): wave wid -> n-tiles {2*wid, 2*wid+1} ----
    f32x4 accs[4][2];
#pragma unroll
    for (int i = 0; i < 4; i++)
#pragma unroll
      for (int j = 0; j < 2; j++) accs[i][j] = (f32x4){0.f, 0.f, 0.f, 0.f};
    {
      int c0 = (lane >> 4) * 8;
#pragma unroll
      for (int kk = 0; kk < 2; kk++) {
        int kc = c0 + kk * 32;
        short8 bf0 = *(const short8*)&Btw[wid * 32 + (lane & 15)][kc];
        short8 bf1 = *(const short8*)&Btw[wid * 32 + 16 + (lane & 15)][kc];
#pragma unroll
        for (int pt = 0; pt < 4; pt++) {
          short8 xfrag = *(const short8*)&Xt[pt * 16 + (lane & 15)][kc];
          accs[pt][0] = mfma_bf16(xfrag, bf0, accs[pt][0]);
          accs[pt][1] = mfma_bf16(xfrag, bf1, accs[pt][1]);
        }
      }
    }
    asm volatile("s_nop 7\n\ts_nop 7" ::);
    // ---- epilogue: Y (in-place, + D*x) ----
    {
      float Dh = Dv[h];
      int p = wid * 16 + (lane & 15);
#pragma unroll
      for (int lt = 0; lt < 4; lt++) {
#pragma unroll
        for (int r = 0; r < 4; r++) {
          int l = lt * 16 + ((lane >> 4) << 2) + r;
          float xv = __bfloat162float(Xt[p][l]);
          Y[(l0 + l) * DI + h * HD + p] = __float2bfloat16(accy[lt][r] + Dh * xv);
        }
      }
    }
    // ---- epilogue: states ----
    {
      size_t sbb = ((((size_t)b * NC + c) * HG + hl) * HD) * DS;
#pragma unroll
      for (int pt = 0; pt < 4; pt++)
#pragma unroll
        for (int tn = 0; tn < 2; tn++)
#pragma unroll
          for (int r = 0; r < 4; r++) {
            int p = pt * 16 + ((lane >> 4) << 2) + r;
            int n = wid * 32 + tn * 16 + (lane & 15);
            states[sbb + (size_t)p * DS + n] = __float2bfloat16(accs[pt][tn][r]);
          }
    }
  }
}

// ---------------- inter-chunk state scan (overwrite with entering state) --------
__global__ void scan_k(bf16* __restrict__ states, const float* __restrict__ cs63,
                       int hbase) {
  int hl = blockIdx.x, b = blockIdx.y, sp = blockIdx.z;
  int tid = threadIdx.x;
  const float* csb = cs63 + ((size_t)b * NH + hbase + hl) * NC;
  int e0 = sp * 1024 + tid * 4;
  float S0 = 0.f, S1 = 0.f, S2 = 0.f, S3 = 0.f;
  for (int c = 0; c < NC; c++) {
    bf16* p = states + ((((size_t)b * NC + c) * HG + hl) * HD) * DS + e0;
    float d = __expf(csb[c]);
    short4v cur = *(const short4v*)p;
    short4v prev;
    prev[0] = bf2s(S0); prev[1] = bf2s(S1); prev[2] = bf2s(S2); prev[3] = bf2s(S3);
    *(short4v*)p = prev;
    S0 = S0 * d + s2f(cur[0]);
    S1 = S1 * d + s2f(cur[1]);
    S2 = S2 * d + s2f(cur[2]);
    S3 = S3 * d + s2f(cur[3]);
  }
}

// ---------------- yoff_k (MFMA): Y += exp(cs)*C·Sprev^T (round-10 verified) ----
__global__ __launch_bounds__(256) void yoff_k(
    const bf16* __restrict__ Cb, const bf16* __restrict__ states,
    const float* __restrict__ dta, int hbase, bf16* __restrict__ Y) {
  __shared__ __align__(16) bf16 Cs[64][136];
  __shared__ __align__(16) bf16 Sp[64][136];
  __shared__ float cs[64];
  int hl = blockIdx.x, c = blockIdx.y, b = blockIdx.z;
  int h = hbase + hl;
  int tid = threadIdx.x;
  int lane = tid & 63, wid = tid >> 6;
  size_t l0 = (size_t)b * L_ + (size_t)c * CK;
  for (int i = tid; i < 64 * 16; i += 256) {
    int r = i >> 4, n8 = (i & 15) << 3;
    *(short8*)&Cs[r][n8] = *(const short8*)&Cb[(l0 + r) * DS + n8];
  }
  size_t sbb = ((((size_t)b * NC + c) * HG + hl) * HD) * DS;
  for (int i = tid; i < 64 * 16; i += 256) {
    int p = i >> 4, n8 = (i & 15) << 3;
    *(short8*)&Sp[p][n8] = *(const short8*)&states[sbb + (size_t)p * DS + n8];
  }
  if (tid < 64) cs[tid] = dta[(size_t)h * BL + l0 + tid];
  __syncthreads();
  if (tid < 64) {
    float a = cs[tid];
#pragma unroll
    for (int o = 1; o < 64; o <<= 1) {
      float t = __shfl_up(a, o, 64);
      if (lane >= o) a += t;
    }
    cs[tid] = a;   // own-slot write, no race
  }
  __syncthreads();
  f32x4 acc[4];
#pragma unroll
  for (int i = 0; i < 4; i++) acc[i] = (f32x4){0.f, 0.f, 0.f, 0.f};
  {
    int prow = wid * 16 + (lane & 15);
    int c0 = (lane >> 4) * 8;
#pragma unroll
    for (int kk = 0; kk < 4; kk++) {
      int kc = c0 + kk * 32;
      short8 sfrag = *(const short8*)&Sp[prow][kc];
#pragma unroll
      for (int lt = 0; lt < 4; lt++) {
        short8 cfrag = *(const short8*)&Cs[lt * 16 + (lane & 15)][kc];
        acc[lt] = mfma_bf16(cfrag, sfrag, acc[lt]);
      }
    }
  }
  asm volatile("s_nop 7\n\ts_nop 7" ::);
  {
    int p = wid * 16 + (lane & 15);
#pragma unroll
    for (int lt = 0; lt < 4; lt++) {
#pragma unroll
      for (int r = 0; r < 4; r++) {
        int l = lt * 16 + ((lane >> 4) << 2) + r;
        float e = __expf(cs[l]);
        size_t idx = (l0 + l) * DI + h * HD + p;
        Y[idx] = __float2bfloat16(__bfloat162float(Y[idx]) + e * acc[lt][r]);
      }
    }
  }
}

// ---------------- gate (z*silu) + RMSNorm -> y bf16 (short8-vectorized) --------
__global__ void gate_k(const bf16* __restrict__ Y, const bf16* __restrict__ z,
                       const float* __restrict__ rms_w, bf16* __restrict__ yb) {
  __shared__ float sm[4];
  int row = blockIdx.x, tid = threadIdx.x;
  int d0 = tid * 8;
  const bf16* Yr = Y + (size_t)row * DI;
  const bf16* zr = z + (size_t)row * DI;
  short8 yv8 = *(const short8*)&Yr[d0];
  short8 zv8 = *(const short8*)&zr[d0];
  float v[8]; float ss = 0.f;
#pragma unroll
  for (int i = 0; i < 8; i++) {
    float yv = s2f(yv8[i]);
    float zz = s2f(zv8[i]);
    yv *= zz / (1.f + __expf(-zz));
    v[i] = yv; ss += yv * yv;
  }
#pragma unroll
  for (int o = 32; o > 0; o >>= 1) ss += __shfl_down(ss, o, 64);
  if ((tid & 63) == 0) sm[tid >> 6] = ss;
  __syncthreads();
  float rstd = rsqrtf((sm[0] + sm[1] + sm[2] + sm[3]) * (1.f / DI) + 1e-5f);
  short8 o8;
#pragma unroll
  for (int i = 0; i < 8; i++) o8[i] = bf2s(v[i] * rstd * rms_w[d0 + i]);
  *(short8*)&yb[(size_t)row * DI + d0] = o8;
}

// ---------------- launcher ----------------
extern "C" void kernel_launch(void* const* d_in, const int* in_sizes, int n_in,
                              void* d_out, int out_size, void* d_ws, size_t ws_size,
                              hipStream_t stream) {
  const float* x       = (const float*)d_in[0];
  const float* ln_w    = (const float*)d_in[1];
  const float* ln_b    = (const float*)d_in[2];
  const float* W_in    = (const float*)d_in[3];
  const float* conv_w  = (const float*)d_in[4];
  const float* conv_b  = (const float*)d_in[5];
  const float* dt_bias = (const float*)d_in[6];
  const float* A_log   = (const float*)d_in[7];
  const float* Dv      = (const float*)d_in[8];
  const float* rms_w   = (const float*)d_in[9];
  const float* W_out   = (const float*)d_in[10];
  float* out = (float*)d_out;

  char* ws = (char*)d_ws;
  size_t off = 0;
  auto alloc = [&](size_t bytes) -> void* {
    void* p = ws + off;
    off += (bytes + 255) & ~(size_t)255;
    return p;
  };
  // ---- ~165 MB total (proven budget); states 64 MB inside R1 ----
  bf16*  W_in_b  = (bf16*)alloc((size_t)NWPAD * DM * 2);
  bf16*  W_out_b = (bf16*)alloc((size_t)DM * DI * 2);
  bf16*  R1      = (bf16*)alloc((size_t)BL * XW * 2);   // 76MB: xBCdt -> states(64MB) -> yb
  bf16*  R2      = (bf16*)alloc((size_t)BL * DI * 2);   // xn -> xs/Y
  bf16*  Bb      = (bf16*)alloc((size_t)BL * DS * 2);
  bf16*  Cb      = (bf16*)alloc((size_t)BL * DS * 2);
  float* dtsp    = (float*)alloc((size_t)BL * NH * 4);  // [h][b*l]
  float* dta     = (float*)alloc((size_t)BL * NH * 4);  // [h][b*l]
  float* cs63    = (float*)alloc((size_t)B_ * NH * NC * 4);
  bf16* xbcdt  = R1;
  bf16* states = R1;
  bf16* yb     = R1;
  bf16* xn     = R2;
  bf16* xsb    = R2;
  bf16* zbuf   = (bf16*)d_out;
  (void)ws_size; (void)in_sizes; (void)n_in; (void)out_size;

  cvt_k <<<(NWPAD * DM + DM * DI) / 256, 256, 0, stream>>>(W_in, W_out, W_in_b, W_out_b);
  ln_k  <<<BL, 256, 0, stream>>>(x, ln_w, ln_b, xn);
  gemm_inproj_k<<<dim3(NWPAD / 128, BL / 128), 256, 0, stream>>>(
      xn, W_in_b, zbuf, xbcdt);
  conv_k<<<dim3(CONVD / 256, L_ / 16, B_), 256, 0, stream>>>(
      xbcdt, conv_w, conv_b, xsb, Bb, Cb);
  dt_k  <<<(BL * NH) / 256, 256, 0, stream>>>(xbcdt, dt_bias, A_log, dtsp, dta);
  for (int g = 0; g < NGRP; g++) {   // NGRP = 2, HG = 16
    int hbase = g * HG;
    chunk_g_k<<<dim3(2, NC, B_), 256, 0, stream>>>(xsb, Bb, Cb, dtsp, dta, Dv, hbase,
                                                   xsb /*Y in place*/, states, cs63);
    scan_k   <<<dim3(HG, B_, 8), 256, 0, stream>>>(states, cs63, hbase);
    yoff_k   <<<dim3(HG, NC, B_), 256, 0, stream>>>(Cb, states, dta, hbase, xsb /*Y*/);
  }
  gate_k<<<BL, 256, 0, stream>>>(xsb /*Y*/, zbuf, rms_w, yb);
  gemm_out_k<<<dim3(DM / 128, BL / 128), 256, 0, stream>>>(yb, W_out_b, out, x);
}

// Round 6
// 578.332 us; speedup vs baseline: 1.0138x; 1.0138x over previous
//
#include <hip/hip_runtime.h>
#include <hip/hip_bf16.h>
#include <math.h>

typedef __hip_bfloat16 bf16;
typedef short short8 __attribute__((ext_vector_type(8)));
typedef short short4v __attribute__((ext_vector_type(4)));
typedef float f32x4 __attribute__((ext_vector_type(4)));

#define B_ 8
#define L_ 2048
#define DM 1024
#define DI 2048
#define NH 32
#define HD 64
#define DS 128
#define NWPAD 4480     // padded W_in rows: 4384 -> 35*128 (128-tile inproj GEMM)
#define XW 2432        // xBCdt width: 2336 -> 19*128
#define CONVD 2304
#define NC 32
#define CK 64
#define HG 16          // heads per SSD group (states buffer granularity)
#define NGRP (NH / HG)
#define BL (B_ * L_)

// ---------------- MFMA via inline asm ----------------
static __device__ __forceinline__ f32x4 mfma_bf16(short8 a, short8 b, f32x4 c) {
  asm("v_mfma_f32_16x16x32_bf16 %0, %1, %2, %0" : "+v"(c) : "v"(a), "v"(b));
  return c;
}

static __device__ __forceinline__ void gload16(const bf16* g, bf16* l) {
  __builtin_amdgcn_global_load_lds((const __attribute__((address_space(1))) void*)g,
                                   (__attribute__((address_space(3))) void*)l, 16, 0, 0);
}

static __device__ __forceinline__ short bf2s(float f) {
  bf16 b = __float2bfloat16(f);
  return *reinterpret_cast<short*>(&b);
}

static __device__ __forceinline__ float s2f(short s) {
  unsigned int u = ((unsigned int)(unsigned short)s) << 16;
  return __uint_as_float(u);
}

// ---------------- weight conversion (merged, index-verified) ----------------
__global__ void cvt_k(const float* __restrict__ Wi, const float* __restrict__ Wo,
                      bf16* __restrict__ Wib, bf16* __restrict__ Wob) {
  size_t i = (size_t)blockIdx.x * 256 + threadIdx.x;
  const size_t NWI = (size_t)NWPAD * DM;          // 4587520
  if (i < NWI) {
    float v = (i < (size_t)4384 * 1024) ? Wi[i] : 0.f;   // zero-pad rows 4384..4479
    Wib[i] = __float2bfloat16(v);
  } else {
    size_t j = i - NWI;                            // < DM*DI
    Wob[j] = __float2bfloat16(Wo[j]);
  }
}

// ---------------- LayerNorm -> bf16 (float4-vectorized) ----------------
__global__ void ln_k(const float* __restrict__ x, const float* __restrict__ w,
                     const float* __restrict__ bz, bf16* __restrict__ xn) {
  __shared__ float sm1[4], sm2[4];
  int row = blockIdx.x, tid = threadIdx.x;
  int d0 = tid * 4;
  const float* xr = x + (size_t)row * DM;
  float4 v4 = *(const float4*)&xr[d0];
  float v[4] = {v4.x, v4.y, v4.z, v4.w};
  float s = v[0] + v[1] + v[2] + v[3];
#pragma unroll
  for (int o = 32; o > 0; o >>= 1) s += __shfl_down(s, o, 64);
  if ((tid & 63) == 0) sm1[tid >> 6] = s;
  __syncthreads();
  float mean = (sm1[0] + sm1[1] + sm1[2] + sm1[3]) * (1.f / DM);
  float q = 0.f;
#pragma unroll
  for (int i = 0; i < 4; i++) { float d = v[i] - mean; q += d * d; }
#pragma unroll
  for (int o = 32; o > 0; o >>= 1) q += __shfl_down(q, o, 64);
  if ((tid & 63) == 0) sm2[tid >> 6] = q;
  __syncthreads();
  float rstd = rsqrtf((sm2[0] + sm2[1] + sm2[2] + sm2[3]) * (1.f / DM) + 1e-5f);
  float4 w4 = *(const float4*)&w[d0];
  float4 b4 = *(const float4*)&bz[d0];
  short4v o4;
  o4[0] = bf2s((v[0] - mean) * rstd * w4.x + b4.x);
  o4[1] = bf2s((v[1] - mean) * rstd * w4.y + b4.y);
  o4[2] = bf2s((v[2] - mean) * rstd * w4.z + b4.z);
  o4[3] = bf2s((v[3] - mean) * rstd * w4.w + b4.w);
  *(short4v*)&xn[(size_t)row * DM + d0] = o4;
}

// ============ 128x128 2-phase GEMM core (proven 865 TF, row-mode swizzle) ============
#define GEMM_PROLOGUE(Kdim)                                                     \
  const int tid = threadIdx.x;                                                  \
  const int lane = tid & 63;                                                    \
  const int wave = tid >> 6;                                                    \
  int nwg = gridDim.x * gridDim.y;                                              \
  int id = blockIdx.y * gridDim.x + blockIdx.x;                                 \
  int bx = blockIdx.x, by = blockIdx.y;                                         \
  if ((nwg & 7) == 0) {                                                         \
    int swz = (id & 7) * (nwg >> 3) + (id >> 3);                                \
    bx = swz % gridDim.x;                                                       \
    by = swz / gridDim.x;                                                       \
  }                                                                             \
  const int m0 = by * 128, n0 = bx * 128;                                       \
  const int wm = (wave >> 1) * 64, wn = (wave & 1) * 64;                        \
  const int srow = tid >> 3;                                                    \
  const int schunk = tid & 7;                                                   \
  f32x4 acc[4][4];                                                              \
  _Pragma("unroll")                                                             \
  for (int i = 0; i < 4; i++)                                                   \
    _Pragma("unroll")                                                           \
    for (int j = 0; j < 4; j++) acc[i][j] = (f32x4){0.f, 0.f, 0.f, 0.f};        \
  for (int kt = 0; kt < (Kdim); kt += 64) {                                     \
    __syncthreads();                                                            \
    _Pragma("unroll")                                                           \
    for (int is = 0; is < 4; is++) {                                            \
      int row = is * 32 + srow;                                                 \
      int gcol = (schunk ^ (row & 7)) << 3;                                     \
      const bf16* ga = A + (size_t)(m0 + row) * (Kdim) + kt + gcol;             \
      const bf16* gb = Bw + (size_t)(n0 + row) * (Kdim) + kt + gcol;            \
      bf16* la = &As[(is * 32 + wave * 8) * 64];                                \
      bf16* lb = &Bs[(is * 32 + wave * 8) * 64];                                \
      gload16(ga, la);                                                          \
      gload16(gb, lb);                                                          \
    }                                                                           \
    __syncthreads();                                                            \
    _Pragma("unroll")                                                           \
    for (int kk = 0; kk < 2; kk++) {                                            \
      short8 af[4], bfr[4];                                                     \
      int mrow = lane & 15;                                                     \
      int kch = kk * 4 + (lane >> 4);                                           \
      _Pragma("unroll")                                                         \
      for (int mi = 0; mi < 4; mi++) {                                          \
        int r = wm + mi * 16 + mrow;                                            \
        af[mi] = *(const short8*)&As[r * 64 + ((kch ^ (r & 7)) << 3)];          \
      }                                                                         \
      _Pragma("unroll")                                                         \
      for (int ni = 0; ni < 4; ni++) {                                          \
        int r = wn + ni * 16 + mrow;                                            \
        bfr[ni] = *(const short8*)&Bs[r * 64 + ((kch ^ (r & 7)) << 3)];         \
      }                                                                         \
      _Pragma("unroll")                                                         \
      for (int mi = 0; mi < 4; mi++)                                            \
        _Pragma("unroll")                                                       \
        for (int ni = 0; ni < 4; ni++)                                          \
          acc[mi][ni] = mfma_bf16(af[mi], bfr[ni], acc[mi][ni]);                \
    }                                                                           \
  }                                                                             \
  asm volatile("s_nop 7\n\ts_nop 7" ::);                                        \
  const int orow = (lane >> 4) << 2;                                            \
  const int ocol = lane & 15;

// ---------------- merged in-proj GEMM: z -> zb, xBCdt -> xb, dt fused ----------
// dt fusion: columns cc in [DI+CONVD, DI+CONVD+NH) hold raw dt. The epilogue
// already has the f32 value in acc -> compute softplus + A*dt here and write
// dtsp/dta [h][b*l] directly. Replaces dt_k's 512K uncoalesced bf16 reads
// (1 cache line per element) with in-register math; dt is now computed from
// f32 (closer to reference than the old bf16 round-trip).
__global__ __launch_bounds__(256) void gemm_inproj_k(
    const bf16* __restrict__ A, const bf16* __restrict__ Bw,
    bf16* __restrict__ zb, bf16* __restrict__ xb,
    const float* __restrict__ dt_bias, const float* __restrict__ A_log,
    float* __restrict__ dtsp, float* __restrict__ dta) {
  __shared__ bf16 As[128 * 64];
  __shared__ bf16 Bs[128 * 64];
  GEMM_PROLOGUE(DM)
#pragma unroll
  for (int mi = 0; mi < 4; mi++) {
#pragma unroll
    for (int ni = 0; ni < 4; ni++) {
      int rbase = m0 + wm + mi * 16 + orow;
      int cc = n0 + wn + ni * 16 + ocol;
#pragma unroll
      for (int r = 0; r < 4; r++) {
        bf16 v = __float2bfloat16(acc[mi][ni][r]);
        if (cc < DI) zb[(size_t)(rbase + r) * DI + cc] = v;
        else         xb[(size_t)(rbase + r) * XW + (cc - DI)] = v;
      }
      if (cc >= DI + CONVD && cc < DI + CONVD + NH) {
        int h = cc - DI - CONVD;
        float bias = dt_bias[h];
        float nA = -__expf(A_log[h]);
#pragma unroll
        for (int r = 0; r < 4; r++) {
          float raw = acc[mi][ni][r] + bias;
          float sp = (raw > 20.f) ? raw : log1pf(__expf(raw));
          size_t idx = (size_t)h * BL + (rbase + r);
          dtsp[idx] = sp;
          dta[idx] = nA * sp;
        }
      }
    }
  }
}

// ---------------- out-proj GEMM: f32 out + residual (128², proven) ----------------
__global__ __launch_bounds__(256) void gemm_out_k(
    const bf16* __restrict__ A, const bf16* __restrict__ Bw,
    float* __restrict__ C, const float* __restrict__ resid) {
  __shared__ bf16 As[128 * 64];
  __shared__ bf16 Bs[128 * 64];
  GEMM_PROLOGUE(DI)
#pragma unroll
  for (int mi = 0; mi < 4; mi++) {
#pragma unroll
    for (int ni = 0; ni < 4; ni++) {
      int rbase = m0 + wm + mi * 16 + orow;
      int cc = n0 + wn + ni * 16 + ocol;
#pragma unroll
      for (int r = 0; r < 4; r++) {
        size_t idx = (size_t)(rbase + r) * DM + cc;
        C[idx] = acc[mi][ni][r] + resid[idx];
      }
    }
  }
}

// ---------------- causal depthwise conv4 + SiLU, split into xs/B/C -------------
__global__ void conv_k(const bf16* __restrict__ xbc, const float* __restrict__ conv_w,
                       const float* __restrict__ conv_b, bf16* __restrict__ xsb,
                       bf16* __restrict__ Bb, bf16* __restrict__ Cb) {
  int c = blockIdx.x * 256 + threadIdx.x;   // 0..2303
  int lbase = blockIdx.y * 16;
  int b = blockIdx.z;
  float4 w = ((const float4*)conv_w)[c];
  float bias = conv_b[c];
  const bf16* xp = xbc + (size_t)b * L_ * XW + c;
  float h0 = 0.f, h1 = 0.f, h2 = 0.f;
  if (lbase > 0) {
    h0 = __bfloat162float(xp[(size_t)(lbase - 3) * XW]);
    h1 = __bfloat162float(xp[(size_t)(lbase - 2) * XW]);
    h2 = __bfloat162float(xp[(size_t)(lbase - 1) * XW]);
  }
  for (int t = 0; t < 16; t++) {
    int l = lbase + t;
    float x3 = __bfloat162float(xp[(size_t)l * XW]);
    float v = bias + w.x * h0 + w.y * h1 + w.z * h2 + w.w * x3;
    v = v / (1.f + __expf(-v));
    bf16 o = __float2bfloat16(v);
    size_t rl = (size_t)b * L_ + l;
    if (c < DI)           xsb[rl * DI + c] = o;
    else if (c < DI + DS) Bb[rl * DS + (c - DI)] = o;
    else                  Cb[rl * DS + (c - DI - DS)] = o;
    h0 = h1; h1 = h2; h2 = x3;
  }
}

// ---------------- chunk_g_k: per (b,c, 8-head subgroup) ----------------
// Stage B/C once, compute G = C.B^T ONCE (head-independent, kept in registers),
// then loop 8 heads reusing the verified per-head fragment code.
__global__ __launch_bounds__(256) void chunk_g_k(
    const bf16* __restrict__ xsb, const bf16* __restrict__ Bb, const bf16* __restrict__ Cb,
    const float* __restrict__ dtsp, const float* __restrict__ dta,
    const float* __restrict__ Dv, int hbase,
    bf16* __restrict__ Y, bf16* __restrict__ states, float* __restrict__ cs63) {
  __shared__ __align__(16) bf16 Bs[64][136];   // B row-major (G + Btw), live whole kernel
  __shared__ __align__(16) bf16 Cs[64][136];   // C row-major (G)
  __shared__ __align__(16) bf16 Btw[128][72];  // B^T * w[l] (per head)
  __shared__ __align__(16) bf16 Xt[64][72];    // X^T (per head)
  __shared__ __align__(16) bf16 Sb[64][72];    // scores (per head)
  __shared__ float cs[64];
  __shared__ float wts[64];
  __shared__ float dts[64];

  int hgsub = blockIdx.x, c = blockIdx.y, b = blockIdx.z;
  int tid = threadIdx.x;
  int lane = tid & 63, wid = tid >> 6;
  size_t l0 = (size_t)b * L_ + (size_t)c * CK;

  // ---- stage Bs, Cs once ----
  for (int i = tid; i < 64 * 16; i += 256) {
    int r = i >> 4, n8 = (i & 15) << 3;
    *(short8*)&Bs[r][n8] = *(const short8*)&Bb[(l0 + r) * DS + n8];
    *(short8*)&Cs[r][n8] = *(const short8*)&Cb[(l0 + r) * DS + n8];
  }
  __syncthreads();

  // ---- G = C·B^T once (K=128): wave wid -> s-tile wid, 4 l-tiles ----
  f32x4 accg[4];
#pragma unroll
  for (int i = 0; i < 4; i++) accg[i] = (f32x4){0.f, 0.f, 0.f, 0.f};
  {
    int rb = wid * 16 + (lane & 15);
    int c0 = (lane >> 4) * 8;
#pragma unroll
    for (int kk = 0; kk < 4; kk++) {
      int kc = c0 + kk * 32;
      short8 bfrag = *(const short8*)&Bs[rb][kc];
#pragma unroll
      for (int lt = 0; lt < 4; lt++) {
        short8 afrag = *(const short8*)&Cs[lt * 16 + (lane & 15)][kc];
        accg[lt] = mfma_bf16(afrag, bfrag, accg[lt]);
      }
    }
  }
  asm volatile("s_nop 7\n\ts_nop 7" ::);

  for (int hh = 0; hh < 8; hh++) {
    int hl = hgsub * 8 + hh;         // local index within HG=16 group
    int h = hbase + hl;
    __syncthreads();                 // prior head's readers of Xt/Btw/Sb done

    // ---- stage Xt via gather-transpose ----
    {
      const bf16* xp = xsb + l0 * DI + h * HD + lane;
      for (int oct = wid; oct < 8; oct += 4) {
        int lb = oct * 8;
        short8 v;
#pragma unroll
        for (int j = 0; j < 8; j++)
          v[j] = *(const short*)&xp[(size_t)(lb + j) * DI];
        *(short8*)&Xt[lane][lb] = v;
      }
    }
    if (tid < 64) {
      dts[tid] = dtsp[(size_t)h * BL + l0 + tid];
      wts[tid] = dta[(size_t)h * BL + l0 + tid];
    }
    __syncthreads();
    // ---- wave-parallel inclusive prefix scan (wave 0) ----
    if (tid < 64) {
      float a = wts[tid];
#pragma unroll
      for (int o = 1; o < 64; o <<= 1) {
        float t = __shfl_up(a, o, 64);
        if (lane >= o) a += t;
      }
      cs[tid] = a;
      float tot = __shfl(a, 63, 64);
      if (tid == 63) cs63[((size_t)b * NH + h) * NC + c] = a;
      wts[tid] = __expf(tot - a) * dts[tid];
    }
    __syncthreads();

    // ---- Btw[n][l] = B[l][n]*w[l] gather (reads Bs + wts) ----
    for (int u = wid; u < 16; u += 4) {
      int nh = u & 1, oct = u >> 1;
      int n = nh * 64 + lane;
      int lb = oct * 8;
      short8 v;
#pragma unroll
      for (int j = 0; j < 8; j++)
        v[j] = bf2s(__bfloat162float(Bs[lb + j][n]) * wts[lb + j]);
      *(short8*)&Btw[n][lb] = v;
    }
    // ---- scores from register accg ----
    {
      int s = wid * 16 + (lane & 15);
      float css = cs[s], dtss = dts[s];
#pragma unroll
      for (int lt = 0; lt < 4; lt++) {
#pragma unroll
        for (int r = 0; r < 4; r++) {
          int l = lt * 16 + ((lane >> 4) << 2) + r;
          float v = (s <= l) ? accg[lt][r] * __expf(cs[l] - css) * dtss : 0.f;
          Sb[l][s] = __float2bfloat16(v);
        }
      }
    }
    __syncthreads();   // Sb + Btw ready

    // ---- Y = Sb·Xt (K=64): wave wid -> p-tile wid ----
    f32x4 accy[4];
#pragma unroll
    for (int i = 0; i < 4; i++) accy[i] = (f32x4){0.f, 0.f, 0.f, 0.f};
    {
      int prow = wid * 16 + (lane & 15);
      int c0 = (lane >> 4) * 8;
#pragma unroll
      for (int kk = 0; kk < 2; kk++) {
        int kc = c0 + kk * 32;
        short8 xfrag = *(const short8*)&Xt[prow][kc];
#pragma unroll
        for (int lt = 0; lt < 4; lt++) {
          short8 sfrag = *(const short8*)&Sb[lt * 16 + (lane & 15)][kc];
          accy[lt] = mfma_bf16(sfrag, xfrag, accy[lt]);
        }
      }
    }
    // ---- states = Xw^T·B (K=64): wave wid -> n-tiles {2*wid, 2*wid+1} ----
    f32x4 accs[4][2];
#pragma unroll
    for (int i = 0; i < 4; i++)
#pragma unroll
      for (int j = 0; j < 2; j++) accs[i][j] = (f32x4){0.f, 0.f, 0.f, 0.f};
    {
      int c0 = (lane >> 4) * 8;
#pragma unroll
      for (int kk = 0; kk < 2; kk++) {
        int kc = c0 + kk * 32;
        short8 bf0 = *(const short8*)&Btw[wid * 32 + (lane & 15)][kc];
        short8 bf1 = *(const short8*)&Btw[wid * 32 + 16 + (lane & 15)][kc];
#pragma unroll
        for (int pt = 0; pt < 4; pt++) {
          short8 xfrag = *(const short8*)&Xt[pt * 16 + (lane & 15)][kc];
          accs[pt][0] = mfma_bf16(xfrag, bf0, accs[pt][0]);
          accs[pt][1] = mfma_bf16(xfrag, bf1, accs[pt][1]);
        }
      }
    }
    asm volatile("s_nop 7\n\ts_nop 7" ::);
    // ---- epilogue: Y (in-place, + D*x) ----
    {
      float Dh = Dv[h];
      int p = wid * 16 + (lane & 15);
#pragma unroll
      for (int lt = 0; lt < 4; lt++) {
#pragma unroll
        for (int r = 0; r < 4; r++) {
          int l = lt * 16 + ((lane >> 4) << 2) + r;
          float xv = __bfloat162float(Xt[p][l]);
          Y[(l0 + l) * DI + h * HD + p] = __float2bfloat16(accy[lt][r] + Dh * xv);
        }
      }
    }
    // ---- epilogue: states ----
    {
      size_t sbb = ((((size_t)b * NC + c) * HG + hl) * HD) * DS;
#pragma unroll
      for (int pt = 0; pt < 4; pt++)
#pragma unroll
        for (int tn = 0; tn < 2; tn++)
#pragma unroll
          for (int r = 0; r < 4; r++) {
            int p = pt * 16 + ((lane >> 4) << 2) + r;
            int n = wid * 32 + tn * 16 + (lane & 15);
            states[sbb + (size_t)p * DS + n] = __float2bfloat16(accs[pt][tn][r]);
          }
    }
  }
}

// ---------------- inter-chunk state scan (overwrite with entering state) --------
__global__ void scan_k(bf16* __restrict__ states, const float* __restrict__ cs63,
                       int hbase) {
  int hl = blockIdx.x, b = blockIdx.y, sp = blockIdx.z;
  int tid = threadIdx.x;
  const float* csb = cs63 + ((size_t)b * NH + hbase + hl) * NC;
  int e0 = sp * 1024 + tid * 4;
  float S0 = 0.f, S1 = 0.f, S2 = 0.f, S3 = 0.f;
  for (int c = 0; c < NC; c++) {
    bf16* p = states + ((((size_t)b * NC + c) * HG + hl) * HD) * DS + e0;
    float d = __expf(csb[c]);
    short4v cur = *(const short4v*)p;
    short4v prev;
    prev[0] = bf2s(S0); prev[1] = bf2s(S1); prev[2] = bf2s(S2); prev[3] = bf2s(S3);
    *(short4v*)p = prev;
    S0 = S0 * d + s2f(cur[0]);
    S1 = S1 * d + s2f(cur[1]);
    S2 = S2 * d + s2f(cur[2]);
    S3 = S3 * d + s2f(cur[3]);
  }
}

// ---------------- yoff_k (MFMA): Y += exp(cs)*C·Sprev^T (round-10 verified) ----
__global__ __launch_bounds__(256) void yoff_k(
    const bf16* __restrict__ Cb, const bf16* __restrict__ states,
    const float* __restrict__ dta, int hbase, bf16* __restrict__ Y) {
  __shared__ __align__(16) bf16 Cs[64][136];
  __shared__ __align__(16) bf16 Sp[64][136];
  __shared__ float cs[64];
  int hl = blockIdx.x, c = blockIdx.y, b = blockIdx.z;
  int h = hbase + hl;
  int tid = threadIdx.x;
  int lane = tid & 63, wid = tid >> 6;
  size_t l0 = (size_t)b * L_ + (size_t)c * CK;
  for (int i = tid; i < 64 * 16; i += 256) {
    int r = i >> 4, n8 = (i & 15) << 3;
    *(short8*)&Cs[r][n8] = *(const short8*)&Cb[(l0 + r) * DS + n8];
  }
  size_t sbb = ((((size_t)b * NC + c) * HG + hl) * HD) * DS;
  for (int i = tid; i < 64 * 16; i += 256) {
    int p = i >> 4, n8 = (i & 15) << 3;
    *(short8*)&Sp[p][n8] = *(const short8*)&states[sbb + (size_t)p * DS + n8];
  }
  if (tid < 64) cs[tid] = dta[(size_t)h * BL + l0 + tid];
  __syncthreads();
  if (tid < 64) {
    float a = cs[tid];
#pragma unroll
    for (int o = 1; o < 64; o <<= 1) {
      float t = __shfl_up(a, o, 64);
      if (lane >= o) a += t;
    }
    cs[tid] = a;   // own-slot write, no race
  }
  __syncthreads();
  f32x4 acc[4];
#pragma unroll
  for (int i = 0; i < 4; i++) acc[i] = (f32x4){0.f, 0.f, 0.f, 0.f};
  {
    int prow = wid * 16 + (lane & 15);
    int c0 = (lane >> 4) * 8;
#pragma unroll
    for (int kk = 0; kk < 4; kk++) {
      int kc = c0 + kk * 32;
      short8 sfrag = *(const short8*)&Sp[prow][kc];
#pragma unroll
      for (int lt = 0; lt < 4; lt++) {
        short8 cfrag = *(const short8*)&Cs[lt * 16 + (lane & 15)][kc];
        acc[lt] = mfma_bf16(cfrag, sfrag, acc[lt]);
      }
    }
  }
  asm volatile("s_nop 7\n\ts_nop 7" ::);
  {
    int p = wid * 16 + (lane & 15);
#pragma unroll
    for (int lt = 0; lt < 4; lt++) {
#pragma unroll
      for (int r = 0; r < 4; r++) {
        int l = lt * 16 + ((lane >> 4) << 2) + r;
        float e = __expf(cs[l]);
        size_t idx = (l0 + l) * DI + h * HD + p;
        Y[idx] = __float2bfloat16(__bfloat162float(Y[idx]) + e * acc[lt][r]);
      }
    }
  }
}

// ---------------- gate (z*silu) + RMSNorm -> y bf16 (short8-vectorized) --------
__global__ void gate_k(const bf16* __restrict__ Y, const bf16* __restrict__ z,
                       const float* __restrict__ rms_w, bf16* __restrict__ yb) {
  __shared__ float sm[4];
  int row = blockIdx.x, tid = threadIdx.x;
  int d0 = tid * 8;
  const bf16* Yr = Y + (size_t)row * DI;
  const bf16* zr = z + (size_t)row * DI;
  short8 yv8 = *(const short8*)&Yr[d0];
  short8 zv8 = *(const short8*)&zr[d0];
  float v[8]; float ss = 0.f;
#pragma unroll
  for (int i = 0; i < 8; i++) {
    float yv = s2f(yv8[i]);
    float zz = s2f(zv8[i]);
    yv *= zz / (1.f + __expf(-zz));
    v[i] = yv; ss += yv * yv;
  }
#pragma unroll
  for (int o = 32; o > 0; o >>= 1) ss += __shfl_down(ss, o, 64);
  if ((tid & 63) == 0) sm[tid >> 6] = ss;
  __syncthreads();
  float rstd = rsqrtf((sm[0] + sm[1] + sm[2] + sm[3]) * (1.f / DI) + 1e-5f);
  short8 o8;
#pragma unroll
  for (int i = 0; i < 8; i++) o8[i] = bf2s(v[i] * rstd * rms_w[d0 + i]);
  *(short8*)&yb[(size_t)row * DI + d0] = o8;
}

// ---------------- launcher ----------------
extern "C" void kernel_launch(void* const* d_in, const int* in_sizes, int n_in,
                              void* d_out, int out_size, void* d_ws, size_t ws_size,
                              hipStream_t stream) {
  const float* x       = (const float*)d_in[0];
  const float* ln_w    = (const float*)d_in[1];
  const float* ln_b    = (const float*)d_in[2];
  const float* W_in    = (const float*)d_in[3];
  const float* conv_w  = (const float*)d_in[4];
  const float* conv_b  = (const float*)d_in[5];
  const float* dt_bias = (const float*)d_in[6];
  const float* A_log   = (const float*)d_in[7];
  const float* Dv      = (const float*)d_in[8];
  const float* rms_w   = (const float*)d_in[9];
  const float* W_out   = (const float*)d_in[10];
  float* out = (float*)d_out;

  char* ws = (char*)d_ws;
  size_t off = 0;
  auto alloc = [&](size_t bytes) -> void* {
    void* p = ws + off;
    off += (bytes + 255) & ~(size_t)255;
    return p;
  };
  // ---- ~165 MB total (proven budget); states 64 MB inside R1 ----
  bf16*  W_in_b  = (bf16*)alloc((size_t)NWPAD * DM * 2);
  bf16*  W_out_b = (bf16*)alloc((size_t)DM * DI * 2);
  bf16*  R1      = (bf16*)alloc((size_t)BL * XW * 2);   // 76MB: xBCdt -> states(64MB) -> yb
  bf16*  R2      = (bf16*)alloc((size_t)BL * DI * 2);   // xn -> xs/Y
  bf16*  Bb      = (bf16*)alloc((size_t)BL * DS * 2);
  bf16*  Cb      = (bf16*)alloc((size_t)BL * DS * 2);
  float* dtsp    = (float*)alloc((size_t)BL * NH * 4);  // [h][b*l]
  float* dta     = (float*)alloc((size_t)BL * NH * 4);  // [h][b*l]
  float* cs63    = (float*)alloc((size_t)B_ * NH * NC * 4);
  bf16* xbcdt  = R1;
  bf16* states = R1;
  bf16* yb     = R1;
  bf16* xn     = R2;
  bf16* xsb    = R2;
  bf16* zbuf   = (bf16*)d_out;
  (void)ws_size; (void)in_sizes; (void)n_in; (void)out_size;

  cvt_k <<<(NWPAD * DM + DM * DI) / 256, 256, 0, stream>>>(W_in, W_out, W_in_b, W_out_b);
  ln_k  <<<BL, 256, 0, stream>>>(x, ln_w, ln_b, xn);
  gemm_inproj_k<<<dim3(NWPAD / 128, BL / 128), 256, 0, stream>>>(
      xn, W_in_b, zbuf, xbcdt, dt_bias, A_log, dtsp, dta);
  conv_k<<<dim3(CONVD / 256, L_ / 16, B_), 256, 0, stream>>>(
      xbcdt, conv_w, conv_b, xsb, Bb, Cb);
  for (int g = 0; g < NGRP; g++) {   // NGRP = 2, HG = 16
    int hbase = g * HG;
    chunk_g_k<<<dim3(2, NC, B_), 256, 0, stream>>>(xsb, Bb, Cb, dtsp, dta, Dv, hbase,
                                                   xsb /*Y in place*/, states, cs63);
    scan_k   <<<dim3(HG, B_, 8), 256, 0, stream>>>(states, cs63, hbase);
    yoff_k   <<<dim3(HG, NC, B_), 256, 0, stream>>>(Cb, states, dta, hbase, xsb /*Y*/);
  }
  gate_k<<<BL, 256, 0, stream>>>(xsb /*Y*/, zbuf, rms_w, yb);
  gemm_out_k<<<dim3(DM / 128, BL / 128), 256, 0, stream>>>(yb, W_out_b, out, x);
}

// Round 7
// 571.944 us; speedup vs baseline: 1.0251x; 1.0112x over previous
//
#include <hip/hip_runtime.h>
#include <hip/hip_bf16.h>
#include <math.h>

typedef __hip_bfloat16 bf16;
typedef short short8 __attribute__((ext_vector_type(8)));
typedef short short4v __attribute__((ext_vector_type(4)));
typedef float f32x4 __attribute__((ext_vector_type(4)));

#define B_ 8
#define L_ 2048
#define DM 1024
#define DI 2048
#define NH 32
#define HD 64
#define DS 128
#define NWPAD 4480     // padded W_in rows: 4384 -> 35*128
#define XW 2432        // xBCdt width: 2336 -> 19*128
#define CONVD 2304
#define NC 32
#define CK 64
#define HG 16          // heads per SSD group (states buffer granularity)
#define NGRP (NH / HG)
#define BL (B_ * L_)

// ---------------- MFMA via inline asm ----------------
static __device__ __forceinline__ f32x4 mfma_bf16(short8 a, short8 b, f32x4 c) {
  asm("v_mfma_f32_16x16x32_bf16 %0, %1, %2, %0" : "+v"(c) : "v"(a), "v"(b));
  return c;
}

static __device__ __forceinline__ void gload16(const bf16* g, bf16* l) {
  __builtin_amdgcn_global_load_lds((const __attribute__((address_space(1))) void*)g,
                                   (__attribute__((address_space(3))) void*)l, 16, 0, 0);
}

static __device__ __forceinline__ short bf2s(float f) {
  bf16 b = __float2bfloat16(f);
  return *reinterpret_cast<short*>(&b);
}

static __device__ __forceinline__ float s2f(short s) {
  unsigned int u = ((unsigned int)(unsigned short)s) << 16;
  return __uint_as_float(u);
}

// ---------------- weight conversion (merged, index-verified) ----------------
__global__ void cvt_k(const float* __restrict__ Wi, const float* __restrict__ Wo,
                      bf16* __restrict__ Wib, bf16* __restrict__ Wob) {
  size_t i = (size_t)blockIdx.x * 256 + threadIdx.x;
  const size_t NWI = (size_t)NWPAD * DM;          // 4587520
  if (i < NWI) {
    float v = (i < (size_t)4384 * 1024) ? Wi[i] : 0.f;   // zero-pad rows 4384..4479
    Wib[i] = __float2bfloat16(v);
  } else {
    size_t j = i - NWI;                            // < DM*DI
    Wob[j] = __float2bfloat16(Wo[j]);
  }
}

// ---------------- LayerNorm -> bf16 (float4-vectorized) ----------------
__global__ void ln_k(const float* __restrict__ x, const float* __restrict__ w,
                     const float* __restrict__ bz, bf16* __restrict__ xn) {
  __shared__ float sm1[4], sm2[4];
  int row = blockIdx.x, tid = threadIdx.x;
  int d0 = tid * 4;
  const float* xr = x + (size_t)row * DM;
  float4 v4 = *(const float4*)&xr[d0];
  float v[4] = {v4.x, v4.y, v4.z, v4.w};
  float s = v[0] + v[1] + v[2] + v[3];
#pragma unroll
  for (int o = 32; o > 0; o >>= 1) s += __shfl_down(s, o, 64);
  if ((tid & 63) == 0) sm1[tid >> 6] = s;
  __syncthreads();
  float mean = (sm1[0] + sm1[1] + sm1[2] + sm1[3]) * (1.f / DM);
  float q = 0.f;
#pragma unroll
  for (int i = 0; i < 4; i++) { float d = v[i] - mean; q += d * d; }
#pragma unroll
  for (int o = 32; o > 0; o >>= 1) q += __shfl_down(q, o, 64);
  if ((tid & 63) == 0) sm2[tid >> 6] = q;
  __syncthreads();
  float rstd = rsqrtf((sm2[0] + sm2[1] + sm2[2] + sm2[3]) * (1.f / DM) + 1e-5f);
  float4 w4 = *(const float4*)&w[d0];
  float4 b4 = *(const float4*)&bz[d0];
  short4v o4;
  o4[0] = bf2s((v[0] - mean) * rstd * w4.x + b4.x);
  o4[1] = bf2s((v[1] - mean) * rstd * w4.y + b4.y);
  o4[2] = bf2s((v[2] - mean) * rstd * w4.z + b4.z);
  o4[3] = bf2s((v[3] - mean) * rstd * w4.w + b4.w);
  *(short4v*)&xn[(size_t)row * DM + d0] = o4;
}

// ============ shared GEMM core (128x128 tile, BK=64, XCD swizzle) ============
#define GEMM_PROLOGUE(Kdim)                                                     \
  const int tid = threadIdx.x;                                                  \
  const int lane = tid & 63;                                                    \
  const int wave = tid >> 6;                                                    \
  int nwg = gridDim.x * gridDim.y;                                              \
  int id = blockIdx.y * gridDim.x + blockIdx.x;                                 \
  int bx = blockIdx.x, by = blockIdx.y;                                         \
  if ((nwg & 7) == 0) {                                                         \
    int swz = (id & 7) * (nwg >> 3) + (id >> 3);                                \
    bx = swz % gridDim.x;                                                       \
    by = swz / gridDim.x;                                                       \
  }                                                                             \
  const int m0 = by * 128, n0 = bx * 128;                                       \
  const int wm = (wave >> 1) * 64, wn = (wave & 1) * 64;                        \
  const int srow = tid >> 3;                                                    \
  const int schunk = tid & 7;                                                   \
  f32x4 acc[4][4];                                                              \
  _Pragma("unroll")                                                             \
  for (int i = 0; i < 4; i++)                                                   \
    _Pragma("unroll")                                                           \
    for (int j = 0; j < 4; j++) acc[i][j] = (f32x4){0.f, 0.f, 0.f, 0.f};        \
  for (int kt = 0; kt < (Kdim); kt += 64) {                                     \
    __syncthreads();                                                            \
    _Pragma("unroll")                                                           \
    for (int is = 0; is < 4; is++) {                                            \
      int row = is * 32 + srow;                                                 \
      int gcol = (schunk ^ (row & 7)) << 3;                                     \
      const bf16* ga = A + (size_t)(m0 + row) * (Kdim) + kt + gcol;             \
      const bf16* gb = Bw + (size_t)(n0 + row) * (Kdim) + kt + gcol;            \
      bf16* la = &As[(is * 32 + wave * 8) * 64];                                \
      bf16* lb = &Bs[(is * 32 + wave * 8) * 64];                                \
      gload16(ga, la);                                                          \
      gload16(gb, lb);                                                          \
    }                                                                           \
    __syncthreads();                                                            \
    _Pragma("unroll")                                                           \
    for (int kk = 0; kk < 2; kk++) {                                            \
      short8 af[4], bfr[4];                                                     \
      int mrow = lane & 15;                                                     \
      int kch = kk * 4 + (lane >> 4);                                           \
      _Pragma("unroll")                                                         \
      for (int mi = 0; mi < 4; mi++) {                                          \
        int r = wm + mi * 16 + mrow;                                            \
        af[mi] = *(const short8*)&As[r * 64 + ((kch ^ (r & 7)) << 3)];          \
      }                                                                         \
      _Pragma("unroll")                                                         \
      for (int ni = 0; ni < 4; ni++) {                                          \
        int r = wn + ni * 16 + mrow;                                            \
        bfr[ni] = *(const short8*)&Bs[r * 64 + ((kch ^ (r & 7)) << 3)];         \
      }                                                                         \
      _Pragma("unroll")                                                         \
      for (int mi = 0; mi < 4; mi++)                                            \
        _Pragma("unroll")                                                       \
        for (int ni = 0; ni < 4; ni++)                                          \
          acc[mi][ni] = mfma_bf16(af[mi], bfr[ni], acc[mi][ni]);                \
    }                                                                           \
  }                                                                             \
  asm volatile("s_nop 7\n\ts_nop 7" ::);                                        \
  const int orow = (lane >> 4) << 2;                                            \
  const int ocol = lane & 15;

// ---------------- merged in-proj GEMM: z -> zb, xBCdt -> xb ----------------
__global__ __launch_bounds__(256) void gemm_inproj_k(
    const bf16* __restrict__ A, const bf16* __restrict__ Bw,
    bf16* __restrict__ zb, bf16* __restrict__ xb) {
  __shared__ bf16 As[128 * 64];
  __shared__ bf16 Bs[128 * 64];
  GEMM_PROLOGUE(DM)
#pragma unroll
  for (int mi = 0; mi < 4; mi++) {
#pragma unroll
    for (int ni = 0; ni < 4; ni++) {
      int rbase = m0 + wm + mi * 16 + orow;
      int cc = n0 + wn + ni * 16 + ocol;
#pragma unroll
      for (int r = 0; r < 4; r++) {
        bf16 v = __float2bfloat16(acc[mi][ni][r]);
        if (cc < DI) zb[(size_t)(rbase + r) * DI + cc] = v;
        else         xb[(size_t)(rbase + r) * XW + (cc - DI)] = v;
      }
    }
  }
}

// ---------------- out-proj GEMM: f32 out + residual ----------------
__global__ __launch_bounds__(256) void gemm_out_k(
    const bf16* __restrict__ A, const bf16* __restrict__ Bw,
    float* __restrict__ C, const float* __restrict__ resid) {
  __shared__ bf16 As[128 * 64];
  __shared__ bf16 Bs[128 * 64];
  GEMM_PROLOGUE(DI)
#pragma unroll
  for (int mi = 0; mi < 4; mi++) {
#pragma unroll
    for (int ni = 0; ni < 4; ni++) {
      int rbase = m0 + wm + mi * 16 + orow;
      int cc = n0 + wn + ni * 16 + ocol;
#pragma unroll
      for (int r = 0; r < 4; r++) {
        size_t idx = (size_t)(rbase + r) * DM + cc;
        C[idx] = acc[mi][ni][r] + resid[idx];
      }
    }
  }
}

// ---------------- causal depthwise conv4 + SiLU, split into xs/B/C -------------
__global__ void conv_k(const bf16* __restrict__ xbc, const float* __restrict__ conv_w,
                       const float* __restrict__ conv_b, bf16* __restrict__ xsb,
                       bf16* __restrict__ Bb, bf16* __restrict__ Cb) {
  int c = blockIdx.x * 256 + threadIdx.x;   // 0..2303
  int lbase = blockIdx.y * 16;
  int b = blockIdx.z;
  float4 w = ((const float4*)conv_w)[c];
  float bias = conv_b[c];
  const bf16* xp = xbc + (size_t)b * L_ * XW + c;
  float h0 = 0.f, h1 = 0.f, h2 = 0.f;
  if (lbase > 0) {
    h0 = __bfloat162float(xp[(size_t)(lbase - 3) * XW]);
    h1 = __bfloat162float(xp[(size_t)(lbase - 2) * XW]);
    h2 = __bfloat162float(xp[(size_t)(lbase - 1) * XW]);
  }
  for (int t = 0; t < 16; t++) {
    int l = lbase + t;
    float x3 = __bfloat162float(xp[(size_t)l * XW]);
    float v = bias + w.x * h0 + w.y * h1 + w.z * h2 + w.w * x3;
    v = v / (1.f + __expf(-v));
    bf16 o = __float2bfloat16(v);
    size_t rl = (size_t)b * L_ + l;
    if (c < DI)           xsb[rl * DI + c] = o;
    else if (c < DI + DS) Bb[rl * DS + (c - DI)] = o;
    else                  Cb[rl * DS + (c - DI - DS)] = o;
    h0 = h1; h1 = h2; h2 = x3;
  }
}

// ---------------- dt: softplus + A*dt (fp32), layout [h][b*l] ----------------
// LDS-transpose rewrite: the 32 dt values per row are CONTIGUOUS in xbcdt
// (64 B at row*XW+CONVD). Old version read 1 bf16/thread at stride 4864 B
// (one 64B line per 2B used, 32x overfetch, latency-bound). New: each block
// loads 64 rows x 32 h via short8 (all bytes of each fetched line used),
// transposes through padded LDS, computes softplus, writes h-major float4s
// (coalesced). Reads the SAME bf16 values => numerics identical.
__global__ __launch_bounds__(256) void dt_k(
    const bf16* __restrict__ xbc, const float* __restrict__ dt_bias,
    const float* __restrict__ A_log, float* __restrict__ dtsp,
    float* __restrict__ dta) {
  __shared__ short sd[64][34];   // [row][h], pad 34 (17 dwords/row, conflict-free cols)
  int tid = threadIdx.x;
  int row0 = blockIdx.x * 64;    // 256 blocks cover BL=16384 rows
  {
    int r = tid >> 2, ch = tid & 3;            // 64 rows x 4 chunks of 8 h
    short8 v = *(const short8*)&xbc[(size_t)(row0 + r) * XW + CONVD + ch * 8];
    *(short8*)&sd[r][ch * 8] = v;              // 16B store, row-padded
  }
  __syncthreads();
  int h = tid >> 3;              // 0..31
  int rr0 = (tid & 7) * 8;       // 8 rows per thread
  float bias = dt_bias[h];
  float nA = -__expf(A_log[h]);
  float sp[8];
#pragma unroll
  for (int j = 0; j < 8; j++) {
    float raw = s2f(sd[rr0 + j][h]) + bias;
    sp[j] = (raw > 20.f) ? raw : log1pf(__expf(raw));
  }
  size_t base = (size_t)h * BL + row0 + rr0;   // 8-aligned -> float4 ok
  float4 a0 = {sp[0], sp[1], sp[2], sp[3]};
  float4 a1 = {sp[4], sp[5], sp[6], sp[7]};
  *(float4*)&dtsp[base]     = a0;
  *(float4*)&dtsp[base + 4] = a1;
  float4 b0 = {nA * sp[0], nA * sp[1], nA * sp[2], nA * sp[3]};
  float4 b1 = {nA * sp[4], nA * sp[5], nA * sp[6], nA * sp[7]};
  *(float4*)&dta[base]     = b0;
  *(float4*)&dta[base + 4] = b1;
}

// ---------------- chunk_g_k: per (b,c, 8-head subgroup) ----------------
// Stage B/C once, compute G = C.B^T ONCE (head-independent, kept in registers),
// then loop 8 heads reusing the verified per-head fragment code.
__global__ __launch_bounds__(256) void chunk_g_k(
    const bf16* __restrict__ xsb, const bf16* __restrict__ Bb, const bf16* __restrict__ Cb,
    const float* __restrict__ dtsp, const float* __restrict__ dta,
    const float* __restrict__ Dv, int hbase,
    bf16* __restrict__ Y, bf16* __restrict__ states, float* __restrict__ cs63) {
  __shared__ __align__(16) bf16 Bs[64][136];   // B row-major (G + Btw), live whole kernel
  __shared__ __align__(16) bf16 Cs[64][136];   // C row-major (G)
  __shared__ __align__(16) bf16 Btw[128][72];  // B^T * w[l] (per head)
  __shared__ __align__(16) bf16 Xt[64][72];    // X^T (per head)
  __shared__ __align__(16) bf16 Sb[64][72];    // scores (per head)
  __shared__ float cs[64];
  __shared__ float wts[64];
  __shared__ float dts[64];

  int hgsub = blockIdx.x, c = blockIdx.y, b = blockIdx.z;
  int tid = threadIdx.x;
  int lane = tid & 63, wid = tid >> 6;
  size_t l0 = (size_t)b * L_ + (size_t)c * CK;

  // ---- stage Bs, Cs once ----
  for (int i = tid; i < 64 * 16; i += 256) {
    int r = i >> 4, n8 = (i & 15) << 3;
    *(short8*)&Bs[r][n8] = *(const short8*)&Bb[(l0 + r) * DS + n8];
    *(short8*)&Cs[r][n8] = *(const short8*)&Cb[(l0 + r) * DS + n8];
  }
  __syncthreads();

  // ---- G = C·B^T once (K=128): wave wid -> s-tile wid, 4 l-tiles ----
  f32x4 accg[4];
#pragma unroll
  for (int i = 0; i < 4; i++) accg[i] = (f32x4){0.f, 0.f, 0.f, 0.f};
  {
    int rb = wid * 16 + (lane & 15);
    int c0 = (lane >> 4) * 8;
#pragma unroll
    for (int kk = 0; kk < 4; kk++) {
      int kc = c0 + kk * 32;
      short8 bfrag = *(const short8*)&Bs[rb][kc];
#pragma unroll
      for (int lt = 0; lt < 4; lt++) {
        short8 afrag = *(const short8*)&Cs[lt * 16 + (lane & 15)][kc];
        accg[lt] = mfma_bf16(afrag, bfrag, accg[lt]);
      }
    }
  }
  asm volatile("s_nop 7\n\ts_nop 7" ::);

  for (int hh = 0; hh < 8; hh++) {
    int hl = hgsub * 8 + hh;         // local index within HG=16 group
    int h = hbase + hl;
    __syncthreads();                 // prior head's readers of Xt/Btw/Sb done

    // ---- stage Xt via gather-transpose ----
    {
      const bf16* xp = xsb + l0 * DI + h * HD + lane;
      for (int oct = wid; oct < 8; oct += 4) {
        int lb = oct * 8;
        short8 v;
#pragma unroll
        for (int j = 0; j < 8; j++)
          v[j] = *(const short*)&xp[(size_t)(lb + j) * DI];
        *(short8*)&Xt[lane][lb] = v;
      }
    }
    if (tid < 64) {
      dts[tid] = dtsp[(size_t)h * BL + l0 + tid];
      wts[tid] = dta[(size_t)h * BL + l0 + tid];
    }
    __syncthreads();
    // ---- wave-parallel inclusive prefix scan (wave 0) ----
    if (tid < 64) {
      float a = wts[tid];
#pragma unroll
      for (int o = 1; o < 64; o <<= 1) {
        float t = __shfl_up(a, o, 64);
        if (lane >= o) a += t;
      }
      cs[tid] = a;
      float tot = __shfl(a, 63, 64);
      if (tid == 63) cs63[((size_t)b * NH + h) * NC + c] = a;
      wts[tid] = __expf(tot - a) * dts[tid];
    }
    __syncthreads();

    // ---- Btw[n][l] = B[l][n]*w[l] gather (reads Bs + wts) ----
    for (int u = wid; u < 16; u += 4) {
      int nh = u & 1, oct = u >> 1;
      int n = nh * 64 + lane;
      int lb = oct * 8;
      short8 v;
#pragma unroll
      for (int j = 0; j < 8; j++)
        v[j] = bf2s(__bfloat162float(Bs[lb + j][n]) * wts[lb + j]);
      *(short8*)&Btw[n][lb] = v;
    }
    // ---- scores from register accg ----
    {
      int s = wid * 16 + (lane & 15);
      float css = cs[s], dtss = dts[s];
#pragma unroll
      for (int lt = 0; lt < 4; lt++) {
#pragma unroll
        for (int r = 0; r < 4; r++) {
          int l = lt * 16 + ((lane >> 4) << 2) + r;
          float v = (s <= l) ? accg[lt][r] * __expf(cs[l] - css) * dtss : 0.f;
          Sb[l][s] = __float2bfloat16(v);
        }
      }
    }
    __syncthreads();   // Sb + Btw ready

    // ---- Y = Sb·Xt (K=64): wave wid -> p-tile wid ----
    f32x4 accy[4];
#pragma unroll
    for (int i = 0; i < 4; i++) accy[i] = (f32x4){0.f, 0.f, 0.f, 0.f};
    {
      int prow = wid * 16 + (lane & 15);
      int c0 = (lane >> 4) * 8;
#pragma unroll
      for (int kk = 0; kk < 2; kk++) {
        int kc = c0 + kk * 32;
        short8 xfrag = *(const short8*)&Xt[prow][kc];
#pragma unroll
        for (int lt = 0; lt < 4; lt++) {
          short8 sfrag = *(const short8*)&Sb[lt * 16 + (lane & 15)][kc];
          accy[lt] = mfma_bf16(sfrag, xfrag, accy[lt]);
        }
      }
    }
    // ---- states = Xw^T·B (K=64): wave wid -> n-tiles {2*wid, 2*wid+1} ----
    f32x4 accs[4][2];
#pragma unroll
    for (int i = 0; i < 4; i++)
#pragma unroll
      for (int j = 0; j < 2; j++) accs[i][j] = (f32x4){0.f, 0.f, 0.f, 0.f};
    {
      int c0 = (lane >> 4) * 8;
#pragma unroll
      for (int kk = 0; kk < 2; kk++) {
        int kc = c0 + kk * 32;
        short8 bf0 = *(const short8*)&Btw[wid * 32 + (lane & 15)][kc];
        short8 bf1 = *(const short8*)&Btw[wid * 32 + 16 + (lane & 15)][kc];
#pragma unroll
        for (int pt = 0; pt < 4; pt++) {
          short8 xfrag = *(const short8*)&Xt[pt * 16 + (lane & 15)][kc];
          accs[pt][0] = mfma_bf16(xfrag, bf0, accs[pt][0]);
          accs[pt][1] = mfma_bf16(xfrag, bf1, accs[pt][1]);
        }
      }
    }
    asm volatile("s_nop 7\n\ts_nop 7" ::);
    // ---- epilogue: Y (in-place, + D*x) ----
    {
      float Dh = Dv[h];
      int p = wid * 16 + (lane & 15);
#pragma unroll
      for (int lt = 0; lt < 4; lt++) {
#pragma unroll
        for (int r = 0; r < 4; r++) {
          int l = lt * 16 + ((lane >> 4) << 2) + r;
          float xv = __bfloat162float(Xt[p][l]);
          Y[(l0 + l) * DI + h * HD + p] = __float2bfloat16(accy[lt][r] + Dh * xv);
        }
      }
    }
    // ---- epilogue: states ----
    {
      size_t sbb = ((((size_t)b * NC + c) * HG + hl) * HD) * DS;
#pragma unroll
      for (int pt = 0; pt < 4; pt++)
#pragma unroll
        for (int tn = 0; tn < 2; tn++)
#pragma unroll
          for (int r = 0; r < 4; r++) {
            int p = pt * 16 + ((lane >> 4) << 2) + r;
            int n = wid * 32 + tn * 16 + (lane & 15);
            states[sbb + (size_t)p * DS + n] = __float2bfloat16(accs[pt][tn][r]);
          }
    }
  }
}

// ---------------- inter-chunk state scan (overwrite with entering state) --------
__global__ void scan_k(bf16* __restrict__ states, const float* __restrict__ cs63,
                       int hbase) {
  int hl = blockIdx.x, b = blockIdx.y, sp = blockIdx.z;
  int tid = threadIdx.x;
  const float* csb = cs63 + ((size_t)b * NH + hbase + hl) * NC;
  int e0 = sp * 1024 + tid * 4;
  float S0 = 0.f, S1 = 0.f, S2 = 0.f, S3 = 0.f;
  for (int c = 0; c < NC; c++) {
    bf16* p = states + ((((size_t)b * NC + c) * HG + hl) * HD) * DS + e0;
    float d = __expf(csb[c]);
    short4v cur = *(const short4v*)p;
    short4v prev;
    prev[0] = bf2s(S0); prev[1] = bf2s(S1); prev[2] = bf2s(S2); prev[3] = bf2s(S3);
    *(short4v*)p = prev;
    S0 = S0 * d + s2f(cur[0]);
    S1 = S1 * d + s2f(cur[1]);
    S2 = S2 * d + s2f(cur[2]);
    S3 = S3 * d + s2f(cur[3]);
  }
}

// ---------------- yoff_k (MFMA): Y += exp(cs)*C·Sprev^T (round-10 verified) ----
__global__ __launch_bounds__(256) void yoff_k(
    const bf16* __restrict__ Cb, const bf16* __restrict__ states,
    const float* __restrict__ dta, int hbase, bf16* __restrict__ Y) {
  __shared__ __align__(16) bf16 Cs[64][136];
  __shared__ __align__(16) bf16 Sp[64][136];
  __shared__ float cs[64];
  int hl = blockIdx.x, c = blockIdx.y, b = blockIdx.z;
  int h = hbase + hl;
  int tid = threadIdx.x;
  int lane = tid & 63, wid = tid >> 6;
  size_t l0 = (size_t)b * L_ + (size_t)c * CK;
  for (int i = tid; i < 64 * 16; i += 256) {
    int r = i >> 4, n8 = (i & 15) << 3;
    *(short8*)&Cs[r][n8] = *(const short8*)&Cb[(l0 + r) * DS + n8];
  }
  size_t sbb = ((((size_t)b * NC + c) * HG + hl) * HD) * DS;
  for (int i = tid; i < 64 * 16; i += 256) {
    int p = i >> 4, n8 = (i & 15) << 3;
    *(short8*)&Sp[p][n8] = *(const short8*)&states[sbb + (size_t)p * DS + n8];
  }
  if (tid < 64) cs[tid] = dta[(size_t)h * BL + l0 + tid];
  __syncthreads();
  if (tid < 64) {
    float a = cs[tid];
#pragma unroll
    for (int o = 1; o < 64; o <<= 1) {
      float t = __shfl_up(a, o, 64);
      if (lane >= o) a += t;
    }
    cs[tid] = a;   // own-slot write, no race
  }
  __syncthreads();
  f32x4 acc[4];
#pragma unroll
  for (int i = 0; i < 4; i++) acc[i] = (f32x4){0.f, 0.f, 0.f, 0.f};
  {
    int prow = wid * 16 + (lane & 15);
    int c0 = (lane >> 4) * 8;
#pragma unroll
    for (int kk = 0; kk < 4; kk++) {
      int kc = c0 + kk * 32;
      short8 sfrag = *(const short8*)&Sp[prow][kc];
#pragma unroll
      for (int lt = 0; lt < 4; lt++) {
        short8 cfrag = *(const short8*)&Cs[lt * 16 + (lane & 15)][kc];
        acc[lt] = mfma_bf16(cfrag, sfrag, acc[lt]);
      }
    }
  }
  asm volatile("s_nop 7\n\ts_nop 7" ::);
  {
    int p = wid * 16 + (lane & 15);
#pragma unroll
    for (int lt = 0; lt < 4; lt++) {
#pragma unroll
      for (int r = 0; r < 4; r++) {
        int l = lt * 16 + ((lane >> 4) << 2) + r;
        float e = __expf(cs[l]);
        size_t idx = (l0 + l) * DI + h * HD + p;
        Y[idx] = __float2bfloat16(__bfloat162float(Y[idx]) + e * acc[lt][r]);
      }
    }
  }
}

// ---------------- gate (z*silu) + RMSNorm -> y bf16 (short8-vectorized) --------
__global__ void gate_k(const bf16* __restrict__ Y, const bf16* __restrict__ z,
                       const float* __restrict__ rms_w, bf16* __restrict__ yb) {
  __shared__ float sm[4];
  int row = blockIdx.x, tid = threadIdx.x;
  int d0 = tid * 8;
  const bf16* Yr = Y + (size_t)row * DI;
  const bf16* zr = z + (size_t)row * DI;
  short8 yv8 = *(const short8*)&Yr[d0];
  short8 zv8 = *(const short8*)&zr[d0];
  float v[8]; float ss = 0.f;
#pragma unroll
  for (int i = 0; i < 8; i++) {
    float yv = s2f(yv8[i]);
    float zz = s2f(zv8[i]);
    yv *= zz / (1.f + __expf(-zz));
    v[i] = yv; ss += yv * yv;
  }
#pragma unroll
  for (int o = 32; o > 0; o >>= 1) ss += __shfl_down(ss, o, 64);
  if ((tid & 63) == 0) sm[tid >> 6] = ss;
  __syncthreads();
  float rstd = rsqrtf((sm[0] + sm[1] + sm[2] + sm[3]) * (1.f / DI) + 1e-5f);
  short8 o8;
#pragma unroll
  for (int i = 0; i < 8; i++) o8[i] = bf2s(v[i] * rstd * rms_w[d0 + i]);
  *(short8*)&yb[(size_t)row * DI + d0] = o8;
}

// ---------------- launcher ----------------
extern "C" void kernel_launch(void* const* d_in, const int* in_sizes, int n_in,
                              void* d_out, int out_size, void* d_ws, size_t ws_size,
                              hipStream_t stream) {
  const float* x       = (const float*)d_in[0];
  const float* ln_w    = (const float*)d_in[1];
  const float* ln_b    = (const float*)d_in[2];
  const float* W_in    = (const float*)d_in[3];
  const float* conv_w  = (const float*)d_in[4];
  const float* conv_b  = (const float*)d_in[5];
  const float* dt_bias = (const float*)d_in[6];
  const float* A_log   = (const float*)d_in[7];
  const float* Dv      = (const float*)d_in[8];
  const float* rms_w   = (const float*)d_in[9];
  const float* W_out   = (const float*)d_in[10];
  float* out = (float*)d_out;

  char* ws = (char*)d_ws;
  size_t off = 0;
  auto alloc = [&](size_t bytes) -> void* {
    void* p = ws + off;
    off += (bytes + 255) & ~(size_t)255;
    return p;
  };
  // ---- ~165 MB total (proven budget); states 64 MB inside R1 ----
  bf16*  W_in_b  = (bf16*)alloc((size_t)NWPAD * DM * 2);
  bf16*  W_out_b = (bf16*)alloc((size_t)DM * DI * 2);
  bf16*  R1      = (bf16*)alloc((size_t)BL * XW * 2);   // 76MB: xBCdt -> states(64MB) -> yb
  bf16*  R2      = (bf16*)alloc((size_t)BL * DI * 2);   // xn -> xs/Y
  bf16*  Bb      = (bf16*)alloc((size_t)BL * DS * 2);
  bf16*  Cb      = (bf16*)alloc((size_t)BL * DS * 2);
  float* dtsp    = (float*)alloc((size_t)BL * NH * 4);  // [h][b*l]
  float* dta     = (float*)alloc((size_t)BL * NH * 4);  // [h][b*l]
  float* cs63    = (float*)alloc((size_t)B_ * NH * NC * 4);
  bf16* xbcdt  = R1;
  bf16* states = R1;
  bf16* yb     = R1;
  bf16* xn     = R2;
  bf16* xsb    = R2;
  bf16* zbuf   = (bf16*)d_out;
  (void)ws_size; (void)in_sizes; (void)n_in; (void)out_size;

  cvt_k <<<(NWPAD * DM + DM * DI) / 256, 256, 0, stream>>>(W_in, W_out, W_in_b, W_out_b);
  ln_k  <<<BL, 256, 0, stream>>>(x, ln_w, ln_b, xn);
  gemm_inproj_k<<<dim3(NWPAD / 128, BL / 128), 256, 0, stream>>>(
      xn, W_in_b, zbuf, xbcdt);
  conv_k<<<dim3(CONVD / 256, L_ / 16, B_), 256, 0, stream>>>(
      xbcdt, conv_w, conv_b, xsb, Bb, Cb);
  dt_k  <<<BL / 64, 256, 0, stream>>>(xbcdt, dt_bias, A_log, dtsp, dta);
  for (int g = 0; g < NGRP; g++) {   // NGRP = 2, HG = 16
    int hbase = g * HG;
    chunk_g_k<<<dim3(2, NC, B_), 256, 0, stream>>>(xsb, Bb, Cb, dtsp, dta, Dv, hbase,
                                                   xsb /*Y in place*/, states, cs63);
    scan_k   <<<dim3(HG, B_, 8), 256, 0, stream>>>(states, cs63, hbase);
    yoff_k   <<<dim3(HG, NC, B_), 256, 0, stream>>>(Cb, states, dta, hbase, xsb /*Y*/);
  }
  gate_k<<<BL, 256, 0, stream>>>(xsb /*Y*/, zbuf, rms_w, yb);
  gemm_out_k<<<dim3(DM / 128, BL / 128), 256, 0, stream>>>(yb, W_out_b, out, x);
}

// Round 8
// 564.837 us; speedup vs baseline: 1.0380x; 1.0126x over previous
//
#include <hip/hip_runtime.h>
#include <hip/hip_bf16.h>
#include <math.h>

typedef __hip_bfloat16 bf16;
typedef short short8 __attribute__((ext_vector_type(8)));
typedef short short4v __attribute__((ext_vector_type(4)));
typedef float f32x4 __attribute__((ext_vector_type(4)));

#define B_ 8
#define L_ 2048
#define DM 1024
#define DI 2048
#define NH 32
#define HD 64
#define DS 128
#define NWPAD 4480     // padded W_in rows: 4384 -> 35*128
#define XW 2432        // xBCdt width: 2336 -> 19*128
#define CONVD 2304
#define NC 32
#define CK 64
#define HG 16          // heads per SSD group (states buffer granularity)
#define NGRP (NH / HG)
#define BL (B_ * L_)
#define NCVT ((NWPAD * DM + DM * DI) / 256)   // 26112 cvt blocks

// ---------------- MFMA via inline asm ----------------
static __device__ __forceinline__ f32x4 mfma_bf16(short8 a, short8 b, f32x4 c) {
  asm("v_mfma_f32_16x16x32_bf16 %0, %1, %2, %0" : "+v"(c) : "v"(a), "v"(b));
  return c;
}

static __device__ __forceinline__ void gload16(const bf16* g, bf16* l) {
  __builtin_amdgcn_global_load_lds((const __attribute__((address_space(1))) void*)g,
                                   (__attribute__((address_space(3))) void*)l, 16, 0, 0);
}

static __device__ __forceinline__ short bf2s(float f) {
  bf16 b = __float2bfloat16(f);
  return *reinterpret_cast<short*>(&b);
}

static __device__ __forceinline__ float s2f(short s) {
  unsigned int u = ((unsigned int)(unsigned short)s) << 16;
  return __uint_as_float(u);
}

// ---------------- prep: weight cvt + LayerNorm merged (independent work) -------
// blocks [0, NCVT): cvt W_in/W_out -> bf16 (index-verified, identical to cvt_k)
// blocks [NCVT, NCVT+BL): LayerNorm row (identical to ln_k)
__global__ void prep_k(const float* __restrict__ Wi, const float* __restrict__ Wo,
                       bf16* __restrict__ Wib, bf16* __restrict__ Wob,
                       const float* __restrict__ x, const float* __restrict__ w,
                       const float* __restrict__ bz, bf16* __restrict__ xn) {
  __shared__ float sm1[4], sm2[4];
  int bid = blockIdx.x, tid = threadIdx.x;
  if (bid < NCVT) {
    size_t i = (size_t)bid * 256 + tid;
    const size_t NWI = (size_t)NWPAD * DM;          // 4587520
    if (i < NWI) {
      float v = (i < (size_t)4384 * 1024) ? Wi[i] : 0.f;   // zero-pad rows 4384..4479
      Wib[i] = __float2bfloat16(v);
    } else {
      size_t j = i - NWI;                            // < DM*DI
      Wob[j] = __float2bfloat16(Wo[j]);
    }
    return;
  }
  int row = bid - NCVT;
  int d0 = tid * 4;
  const float* xr = x + (size_t)row * DM;
  float4 v4 = *(const float4*)&xr[d0];
  float v[4] = {v4.x, v4.y, v4.z, v4.w};
  float s = v[0] + v[1] + v[2] + v[3];
#pragma unroll
  for (int o = 32; o > 0; o >>= 1) s += __shfl_down(s, o, 64);
  if ((tid & 63) == 0) sm1[tid >> 6] = s;
  __syncthreads();
  float mean = (sm1[0] + sm1[1] + sm1[2] + sm1[3]) * (1.f / DM);
  float q = 0.f;
#pragma unroll
  for (int i = 0; i < 4; i++) { float d = v[i] - mean; q += d * d; }
#pragma unroll
  for (int o = 32; o > 0; o >>= 1) q += __shfl_down(q, o, 64);
  if ((tid & 63) == 0) sm2[tid >> 6] = q;
  __syncthreads();
  float rstd = rsqrtf((sm2[0] + sm2[1] + sm2[2] + sm2[3]) * (1.f / DM) + 1e-5f);
  float4 w4 = *(const float4*)&w[d0];
  float4 b4 = *(const float4*)&bz[d0];
  short4v o4;
  o4[0] = bf2s((v[0] - mean) * rstd * w4.x + b4.x);
  o4[1] = bf2s((v[1] - mean) * rstd * w4.y + b4.y);
  o4[2] = bf2s((v[2] - mean) * rstd * w4.z + b4.z);
  o4[3] = bf2s((v[3] - mean) * rstd * w4.w + b4.w);
  *(short4v*)&xn[(size_t)row * DM + d0] = o4;
}

// ============ shared GEMM core (128x128 tile, BK=64, XCD swizzle) ============
#define GEMM_PROLOGUE(Kdim)                                                     \
  const int tid = threadIdx.x;                                                  \
  const int lane = tid & 63;                                                    \
  const int wave = tid >> 6;                                                    \
  int nwg = gridDim.x * gridDim.y;                                              \
  int id = blockIdx.y * gridDim.x + blockIdx.x;                                 \
  int bx = blockIdx.x, by = blockIdx.y;                                         \
  if ((nwg & 7) == 0) {                                                         \
    int swz = (id & 7) * (nwg >> 3) + (id >> 3);                                \
    bx = swz % gridDim.x;                                                       \
    by = swz / gridDim.x;                                                       \
  }                                                                             \
  const int m0 = by * 128, n0 = bx * 128;                                       \
  const int wm = (wave >> 1) * 64, wn = (wave & 1) * 64;                        \
  const int srow = tid >> 3;                                                    \
  const int schunk = tid & 7;                                                   \
  f32x4 acc[4][4];                                                              \
  _Pragma("unroll")                                                             \
  for (int i = 0; i < 4; i++)                                                   \
    _Pragma("unroll")                                                           \
    for (int j = 0; j < 4; j++) acc[i][j] = (f32x4){0.f, 0.f, 0.f, 0.f};        \
  for (int kt = 0; kt < (Kdim); kt += 64) {                                     \
    __syncthreads();                                                            \
    _Pragma("unroll")                                                           \
    for (int is = 0; is < 4; is++) {                                            \
      int row = is * 32 + srow;                                                 \
      int gcol = (schunk ^ (row & 7)) << 3;                                     \
      const bf16* ga = A + (size_t)(m0 + row) * (Kdim) + kt + gcol;             \
      const bf16* gb = Bw + (size_t)(n0 + row) * (Kdim) + kt + gcol;            \
      bf16* la = &As[(is * 32 + wave * 8) * 64];                                \
      bf16* lb = &Bs[(is * 32 + wave * 8) * 64];                                \
      gload16(ga, la);                                                          \
      gload16(gb, lb);                                                          \
    }                                                                           \
    __syncthreads();                                                            \
    _Pragma("unroll")                                                           \
    for (int kk = 0; kk < 2; kk++) {                                            \
      short8 af[4], bfr[4];                                                     \
      int mrow = lane & 15;                                                     \
      int kch = kk * 4 + (lane >> 4);                                           \
      _Pragma("unroll")                                                         \
      for (int mi = 0; mi < 4; mi++) {                                          \
        int r = wm + mi * 16 + mrow;                                            \
        af[mi] = *(const short8*)&As[r * 64 + ((kch ^ (r & 7)) << 3)];          \
      }                                                                         \
      _Pragma("unroll")                                                         \
      for (int ni = 0; ni < 4; ni++) {                                          \
        int r = wn + ni * 16 + mrow;                                            \
        bfr[ni] = *(const short8*)&Bs[r * 64 + ((kch ^ (r & 7)) << 3)];         \
      }                                                                         \
      _Pragma("unroll")                                                         \
      for (int mi = 0; mi < 4; mi++)                                            \
        _Pragma("unroll")                                                       \
        for (int ni = 0; ni < 4; ni++)                                          \
          acc[mi][ni] = mfma_bf16(af[mi], bfr[ni], acc[mi][ni]);                \
    }                                                                           \
  }                                                                             \
  asm volatile("s_nop 7\n\ts_nop 7" ::);                                        \
  const int orow = (lane >> 4) << 2;                                            \
  const int ocol = lane & 15;

// ---------------- merged in-proj GEMM: z -> zb, xBCdt -> xb ----------------
__global__ __launch_bounds__(256) void gemm_inproj_k(
    const bf16* __restrict__ A, const bf16* __restrict__ Bw,
    bf16* __restrict__ zb, bf16* __restrict__ xb) {
  __shared__ bf16 As[128 * 64];
  __shared__ bf16 Bs[128 * 64];
  GEMM_PROLOGUE(DM)
#pragma unroll
  for (int mi = 0; mi < 4; mi++) {
#pragma unroll
    for (int ni = 0; ni < 4; ni++) {
      int rbase = m0 + wm + mi * 16 + orow;
      int cc = n0 + wn + ni * 16 + ocol;
#pragma unroll
      for (int r = 0; r < 4; r++) {
        bf16 v = __float2bfloat16(acc[mi][ni][r]);
        if (cc < DI) zb[(size_t)(rbase + r) * DI + cc] = v;
        else         xb[(size_t)(rbase + r) * XW + (cc - DI)] = v;
      }
    }
  }
}

// ---------------- out-proj GEMM: f32 out + residual ----------------
__global__ __launch_bounds__(256) void gemm_out_k(
    const bf16* __restrict__ A, const bf16* __restrict__ Bw,
    float* __restrict__ C, const float* __restrict__ resid) {
  __shared__ bf16 As[128 * 64];
  __shared__ bf16 Bs[128 * 64];
  GEMM_PROLOGUE(DI)
#pragma unroll
  for (int mi = 0; mi < 4; mi++) {
#pragma unroll
    for (int ni = 0; ni < 4; ni++) {
      int rbase = m0 + wm + mi * 16 + orow;
      int cc = n0 + wn + ni * 16 + ocol;
#pragma unroll
      for (int r = 0; r < 4; r++) {
        size_t idx = (size_t)(rbase + r) * DM + cc;
        C[idx] = acc[mi][ni][r] + resid[idx];
      }
    }
  }
}

// ---------------- conv4+SiLU split + dt (softplus, A*dt) merged ----------------
// bx in [0,9): causal depthwise conv over 256 channels (identical to before).
// bx == 9: dt slice for this (b, 16-row strip): reads the 32 contiguous dt
// bf16s per row, same formula as before -> bit-identical outputs, one fewer
// kernel launch.
__global__ void conv_k(const bf16* __restrict__ xbc, const float* __restrict__ conv_w,
                       const float* __restrict__ conv_b, bf16* __restrict__ xsb,
                       bf16* __restrict__ Bb, bf16* __restrict__ Cb,
                       const float* __restrict__ dt_bias, const float* __restrict__ A_log,
                       float* __restrict__ dtsp, float* __restrict__ dta) {
  int bx = blockIdx.x, tid = threadIdx.x;
  int lbase = blockIdx.y * 16;
  int b = blockIdx.z;
  if (bx == 9) {
    int r = tid & 15;                 // 16 rows; consecutive tid -> coalesced writes
    int h0 = (tid >> 4) * 2;          // 2 heads per thread
    size_t row = (size_t)b * L_ + lbase + r;
    unsigned int u = *(const unsigned int*)&xbc[row * XW + CONVD + h0];
    short sv[2];
    sv[0] = (short)(u & 0xffff);
    sv[1] = (short)(u >> 16);
#pragma unroll
    for (int k = 0; k < 2; k++) {
      int h = h0 + k;
      float raw = s2f(sv[k]) + dt_bias[h];
      float sp = (raw > 20.f) ? raw : log1pf(__expf(raw));
      size_t idx = (size_t)h * BL + row;
      dtsp[idx] = sp;
      dta[idx] = -__expf(A_log[h]) * sp;
    }
    return;
  }
  int c = bx * 256 + tid;   // 0..2303
  float4 w = ((const float4*)conv_w)[c];
  float bias = conv_b[c];
  const bf16* xp = xbc + (size_t)b * L_ * XW + c;
  float h0 = 0.f, h1 = 0.f, h2 = 0.f;
  if (lbase > 0) {
    h0 = __bfloat162float(xp[(size_t)(lbase - 3) * XW]);
    h1 = __bfloat162float(xp[(size_t)(lbase - 2) * XW]);
    h2 = __bfloat162float(xp[(size_t)(lbase - 1) * XW]);
  }
  for (int t = 0; t < 16; t++) {
    int l = lbase + t;
    float x3 = __bfloat162float(xp[(size_t)l * XW]);
    float v = bias + w.x * h0 + w.y * h1 + w.z * h2 + w.w * x3;
    v = v / (1.f + __expf(-v));
    bf16 o = __float2bfloat16(v);
    size_t rl = (size_t)b * L_ + l;
    if (c < DI)           xsb[rl * DI + c] = o;
    else if (c < DI + DS) Bb[rl * DS + (c - DI)] = o;
    else                  Cb[rl * DS + (c - DI - DS)] = o;
    h0 = h1; h1 = h2; h2 = x3;
  }
}

// ---------------- chunk_g_k: per (b,c, 8-head subgroup) ----------------
// Stage B/C once, compute G = C.B^T ONCE (head-independent, kept in registers),
// then loop 8 heads reusing the verified per-head fragment code.
__global__ __launch_bounds__(256) void chunk_g_k(
    const bf16* __restrict__ xsb, const bf16* __restrict__ Bb, const bf16* __restrict__ Cb,
    const float* __restrict__ dtsp, const float* __restrict__ dta,
    const float* __restrict__ Dv, int hbase,
    bf16* __restrict__ Y, bf16* __restrict__ states, float* __restrict__ cs63) {
  __shared__ __align__(16) bf16 Bs[64][136];   // B row-major (G + Btw), live whole kernel
  __shared__ __align__(16) bf16 Cs[64][136];   // C row-major (G)
  __shared__ __align__(16) bf16 Btw[128][72];  // B^T * w[l] (per head)
  __shared__ __align__(16) bf16 Xt[64][72];    // X^T (per head)
  __shared__ __align__(16) bf16 Sb[64][72];    // scores (per head)
  __shared__ float cs[64];
  __shared__ float wts[64];
  __shared__ float dts[64];

  int hgsub = blockIdx.x, c = blockIdx.y, b = blockIdx.z;
  int tid = threadIdx.x;
  int lane = tid & 63, wid = tid >> 6;
  size_t l0 = (size_t)b * L_ + (size_t)c * CK;

  // ---- stage Bs, Cs once ----
  for (int i = tid; i < 64 * 16; i += 256) {
    int r = i >> 4, n8 = (i & 15) << 3;
    *(short8*)&Bs[r][n8] = *(const short8*)&Bb[(l0 + r) * DS + n8];
    *(short8*)&Cs[r][n8] = *(const short8*)&Cb[(l0 + r) * DS + n8];
  }
  __syncthreads();

  // ---- G = C·B^T once (K=128): wave wid -> s-tile wid, 4 l-tiles ----
  f32x4 accg[4];
#pragma unroll
  for (int i = 0; i < 4; i++) accg[i] = (f32x4){0.f, 0.f, 0.f, 0.f};
  {
    int rb = wid * 16 + (lane & 15);
    int c0 = (lane >> 4) * 8;
#pragma unroll
    for (int kk = 0; kk < 4; kk++) {
      int kc = c0 + kk * 32;
      short8 bfrag = *(const short8*)&Bs[rb][kc];
#pragma unroll
      for (int lt = 0; lt < 4; lt++) {
        short8 afrag = *(const short8*)&Cs[lt * 16 + (lane & 15)][kc];
        accg[lt] = mfma_bf16(afrag, bfrag, accg[lt]);
      }
    }
  }
  asm volatile("s_nop 7\n\ts_nop 7" ::);

  for (int hh = 0; hh < 8; hh++) {
    int hl = hgsub * 8 + hh;         // local index within HG=16 group
    int h = hbase + hl;
    __syncthreads();                 // prior head's readers of Xt/Btw/Sb done

    // ---- stage Xt via gather-transpose ----
    {
      const bf16* xp = xsb + l0 * DI + h * HD + lane;
      for (int oct = wid; oct < 8; oct += 4) {
        int lb = oct * 8;
        short8 v;
#pragma unroll
        for (int j = 0; j < 8; j++)
          v[j] = *(const short*)&xp[(size_t)(lb + j) * DI];
        *(short8*)&Xt[lane][lb] = v;
      }
    }
    if (tid < 64) {
      dts[tid] = dtsp[(size_t)h * BL + l0 + tid];
      wts[tid] = dta[(size_t)h * BL + l0 + tid];
    }
    __syncthreads();
    // ---- wave-parallel inclusive prefix scan (wave 0) ----
    if (tid < 64) {
      float a = wts[tid];
#pragma unroll
      for (int o = 1; o < 64; o <<= 1) {
        float t = __shfl_up(a, o, 64);
        if (lane >= o) a += t;
      }
      cs[tid] = a;
      float tot = __shfl(a, 63, 64);
      if (tid == 63) cs63[((size_t)b * NH + h) * NC + c] = a;
      wts[tid] = __expf(tot - a) * dts[tid];
    }
    __syncthreads();

    // ---- Btw[n][l] = B[l][n]*w[l] gather (reads Bs + wts) ----
    for (int u = wid; u < 16; u += 4) {
      int nh = u & 1, oct = u >> 1;
      int n = nh * 64 + lane;
      int lb = oct * 8;
      short8 v;
#pragma unroll
      for (int j = 0; j < 8; j++)
        v[j] = bf2s(__bfloat162float(Bs[lb + j][n]) * wts[lb + j]);
      *(short8*)&Btw[n][lb] = v;
    }
    // ---- scores from register accg ----
    {
      int s = wid * 16 + (lane & 15);
      float css = cs[s], dtss = dts[s];
#pragma unroll
      for (int lt = 0; lt < 4; lt++) {
#pragma unroll
        for (int r = 0; r < 4; r++) {
          int l = lt * 16 + ((lane >> 4) << 2) + r;
          float v = (s <= l) ? accg[lt][r] * __expf(cs[l] - css) * dtss : 0.f;
          Sb[l][s] = __float2bfloat16(v);
        }
      }
    }
    __syncthreads();   // Sb + Btw ready

    // ---- Y = Sb·Xt (K=64): wave wid -> p-tile wid ----
    f32x4 accy[4];
#pragma unroll
    for (int i = 0; i < 4; i++) accy[i] = (f32x4){0.f, 0.f, 0.f, 0.f};
    {
      int prow = wid * 16 + (lane & 15);
      int c0 = (lane >> 4) * 8;
#pragma unroll
      for (int kk = 0; kk < 2; kk++) {
        int kc = c0 + kk * 32;
        short8 xfrag = *(const short8*)&Xt[prow][kc];
#pragma unroll
        for (int lt = 0; lt < 4; lt++) {
          short8 sfrag = *(const short8*)&Sb[lt * 16 + (lane & 15)][kc];
          accy[lt] = mfma_bf16(sfrag, xfrag, accy[lt]);
        }
      }
    }
    // ---- states = Xw^T·B (K=64): wave wid -> n-tiles {2*wid, 2*wid+1} ----
    f32x4 accs[4][2];
#pragma unroll
    for (int i = 0; i < 4; i++)
#pragma unroll
      for (int j = 0; j < 2; j++) accs[i][j] = (f32x4){0.f, 0.f, 0.f, 0.f};
    {
      int c0 = (lane >> 4) * 8;
#pragma unroll
      for (int kk = 0; kk < 2; kk++) {
        int kc = c0 + kk * 32;
        short8 bf0 = *(const short8*)&Btw[wid * 32 + (lane & 15)][kc];
        short8 bf1 = *(const short8*)&Btw[wid * 32 + 16 + (lane & 15)][kc];
#pragma unroll
        for (int pt = 0; pt < 4; pt++) {
          short8 xfrag = *(const short8*)&Xt[pt * 16 + (lane & 15)][kc];
          accs[pt][0] = mfma_bf16(xfrag, bf0, accs[pt][0]);
          accs[pt][1] = mfma_bf16(xfrag, bf1, accs[pt][1]);
        }
      }
    }
    asm volatile("s_nop 7\n\ts_nop 7" ::);
    // ---- epilogue: Y (in-place, + D*x) ----
    {
      float Dh = Dv[h];
      int p = wid * 16 + (lane & 15);
#pragma unroll
      for (int lt = 0; lt < 4; lt++) {
#pragma unroll
        for (int r = 0; r < 4; r++) {
          int l = lt * 16 + ((lane >> 4) << 2) + r;
          float xv = __bfloat162float(Xt[p][l]);
          Y[(l0 + l) * DI + h * HD + p] = __float2bfloat16(accy[lt][r] + Dh * xv);
        }
      }
    }
    // ---- epilogue: states ----
    {
      size_t sbb = ((((size_t)b * NC + c) * HG + hl) * HD) * DS;
#pragma unroll
      for (int pt = 0; pt < 4; pt++)
#pragma unroll
        for (int tn = 0; tn < 2; tn++)
#pragma unroll
          for (int r = 0; r < 4; r++) {
            int p = pt * 16 + ((lane >> 4) << 2) + r;
            int n = wid * 32 + tn * 16 + (lane & 15);
            states[sbb + (size_t)p * DS + n] = __float2bfloat16(accs[pt][tn][r]);
          }
    }
  }
}

// ---------------- inter-chunk state scan (overwrite with entering state) --------
__global__ void scan_k(bf16* __restrict__ states, const float* __restrict__ cs63,
                       int hbase) {
  int hl = blockIdx.x, b = blockIdx.y, sp = blockIdx.z;
  int tid = threadIdx.x;
  const float* csb = cs63 + ((size_t)b * NH + hbase + hl) * NC;
  int e0 = sp * 1024 + tid * 4;
  float S0 = 0.f, S1 = 0.f, S2 = 0.f, S3 = 0.f;
  for (int c = 0; c < NC; c++) {
    bf16* p = states + ((((size_t)b * NC + c) * HG + hl) * HD) * DS + e0;
    float d = __expf(csb[c]);
    short4v cur = *(const short4v*)p;
    short4v prev;
    prev[0] = bf2s(S0); prev[1] = bf2s(S1); prev[2] = bf2s(S2); prev[3] = bf2s(S3);
    *(short4v*)p = prev;
    S0 = S0 * d + s2f(cur[0]);
    S1 = S1 * d + s2f(cur[1]);
    S2 = S2 * d + s2f(cur[2]);
    S3 = S3 * d + s2f(cur[3]);
  }
}

// ---------------- yoff_k (MFMA): Y += exp(cs)*C·Sprev^T (round-10 verified) ----
__global__ __launch_bounds__(256) void yoff_k(
    const bf16* __restrict__ Cb, const bf16* __restrict__ states,
    const float* __restrict__ dta, int hbase, bf16* __restrict__ Y) {
  __shared__ __align__(16) bf16 Cs[64][136];
  __shared__ __align__(16) bf16 Sp[64][136];
  __shared__ float cs[64];
  int hl = blockIdx.x, c = blockIdx.y, b = blockIdx.z;
  int h = hbase + hl;
  int tid = threadIdx.x;
  int lane = tid & 63, wid = tid >> 6;
  size_t l0 = (size_t)b * L_ + (size_t)c * CK;
  for (int i = tid; i < 64 * 16; i += 256) {
    int r = i >> 4, n8 = (i & 15) << 3;
    *(short8*)&Cs[r][n8] = *(const short8*)&Cb[(l0 + r) * DS + n8];
  }
  size_t sbb = ((((size_t)b * NC + c) * HG + hl) * HD) * DS;
  for (int i = tid; i < 64 * 16; i += 256) {
    int p = i >> 4, n8 = (i & 15) << 3;
    *(short8*)&Sp[p][n8] = *(const short8*)&states[sbb + (size_t)p * DS + n8];
  }
  if (tid < 64) cs[tid] = dta[(size_t)h * BL + l0 + tid];
  __syncthreads();
  if (tid < 64) {
    float a = cs[tid];
#pragma unroll
    for (int o = 1; o < 64; o <<= 1) {
      float t = __shfl_up(a, o, 64);
      if (lane >= o) a += t;
    }
    cs[tid] = a;   // own-slot write, no race
  }
  __syncthreads();
  f32x4 acc[4];
#pragma unroll
  for (int i = 0; i < 4; i++) acc[i] = (f32x4){0.f, 0.f, 0.f, 0.f};
  {
    int prow = wid * 16 + (lane & 15);
    int c0 = (lane >> 4) * 8;
#pragma unroll
    for (int kk = 0; kk < 4; kk++) {
      int kc = c0 + kk * 32;
      short8 sfrag = *(const short8*)&Sp[prow][kc];
#pragma unroll
      for (int lt = 0; lt < 4; lt++) {
        short8 cfrag = *(const short8*)&Cs[lt * 16 + (lane & 15)][kc];
        acc[lt] = mfma_bf16(cfrag, sfrag, acc[lt]);
      }
    }
  }
  asm volatile("s_nop 7\n\ts_nop 7" ::);
  {
    int p = wid * 16 + (lane & 15);
#pragma unroll
    for (int lt = 0; lt < 4; lt++) {
#pragma unroll
      for (int r = 0; r < 4; r++) {
        int l = lt * 16 + ((lane >> 4) << 2) + r;
        float e = __expf(cs[l]);
        size_t idx = (l0 + l) * DI + h * HD + p;
        Y[idx] = __float2bfloat16(__bfloat162float(Y[idx]) + e * acc[lt][r]);
      }
    }
  }
}

// ---------------- gate (z*silu) + RMSNorm -> y bf16 (short8-vectorized) --------
__global__ void gate_k(const bf16* __restrict__ Y, const bf16* __restrict__ z,
                       const float* __restrict__ rms_w, bf16* __restrict__ yb) {
  __shared__ float sm[4];
  int row = blockIdx.x, tid = threadIdx.x;
  int d0 = tid * 8;
  const bf16* Yr = Y + (size_t)row * DI;
  const bf16* zr = z + (size_t)row * DI;
  short8 yv8 = *(const short8*)&Yr[d0];
  short8 zv8 = *(const short8*)&zr[d0];
  float v[8]; float ss = 0.f;
#pragma unroll
  for (int i = 0; i < 8; i++) {
    float yv = s2f(yv8[i]);
    float zz = s2f(zv8[i]);
    yv *= zz / (1.f + __expf(-zz));
    v[i] = yv; ss += yv * yv;
  }
#pragma unroll
  for (int o = 32; o > 0; o >>= 1) ss += __shfl_down(ss, o, 64);
  if ((tid & 63) == 0) sm[tid >> 6] = ss;
  __syncthreads();
  float rstd = rsqrtf((sm[0] + sm[1] + sm[2] + sm[3]) * (1.f / DI) + 1e-5f);
  short8 o8;
#pragma unroll
  for (int i = 0; i < 8; i++) o8[i] = bf2s(v[i] * rstd * rms_w[d0 + i]);
  *(short8*)&yb[(size_t)row * DI + d0] = o8;
}

// ---------------- launcher ----------------
extern "C" void kernel_launch(void* const* d_in, const int* in_sizes, int n_in,
                              void* d_out, int out_size, void* d_ws, size_t ws_size,
                              hipStream_t stream) {
  const float* x       = (const float*)d_in[0];
  const float* ln_w    = (const float*)d_in[1];
  const float* ln_b    = (const float*)d_in[2];
  const float* W_in    = (const float*)d_in[3];
  const float* conv_w  = (const float*)d_in[4];
  const float* conv_b  = (const float*)d_in[5];
  const float* dt_bias = (const float*)d_in[6];
  const float* A_log   = (const float*)d_in[7];
  const float* Dv      = (const float*)d_in[8];
  const float* rms_w   = (const float*)d_in[9];
  const float* W_out   = (const float*)d_in[10];
  float* out = (float*)d_out;

  char* ws = (char*)d_ws;
  size_t off = 0;
  auto alloc = [&](size_t bytes) -> void* {
    void* p = ws + off;
    off += (bytes + 255) & ~(size_t)255;
    return p;
  };
  // ---- ~165 MB total (proven budget); states 64 MB inside R1 ----
  bf16*  W_in_b  = (bf16*)alloc((size_t)NWPAD * DM * 2);
  bf16*  W_out_b = (bf16*)alloc((size_t)DM * DI * 2);
  bf16*  R1      = (bf16*)alloc((size_t)BL * XW * 2);   // 76MB: xBCdt -> states(64MB) -> yb
  bf16*  R2      = (bf16*)alloc((size_t)BL * DI * 2);   // xn -> xs/Y
  bf16*  Bb      = (bf16*)alloc((size_t)BL * DS * 2);
  bf16*  Cb      = (bf16*)alloc((size_t)BL * DS * 2);
  float* dtsp    = (float*)alloc((size_t)BL * NH * 4);  // [h][b*l]
  float* dta     = (float*)alloc((size_t)BL * NH * 4);  // [h][b*l]
  float* cs63    = (float*)alloc((size_t)B_ * NH * NC * 4);
  bf16* xbcdt  = R1;
  bf16* states = R1;
  bf16* yb     = R1;
  bf16* xn     = R2;
  bf16* xsb    = R2;
  bf16* zbuf   = (bf16*)d_out;
  (void)ws_size; (void)in_sizes; (void)n_in; (void)out_size;

  prep_k<<<NCVT + BL, 256, 0, stream>>>(W_in, W_out, W_in_b, W_out_b,
                                        x, ln_w, ln_b, xn);
  gemm_inproj_k<<<dim3(NWPAD / 128, BL / 128), 256, 0, stream>>>(
      xn, W_in_b, zbuf, xbcdt);
  conv_k<<<dim3(CONVD / 256 + 1, L_ / 16, B_), 256, 0, stream>>>(
      xbcdt, conv_w, conv_b, xsb, Bb, Cb, dt_bias, A_log, dtsp, dta);
  for (int g = 0; g < NGRP; g++) {   // NGRP = 2, HG = 16
    int hbase = g * HG;
    chunk_g_k<<<dim3(2, NC, B_), 256, 0, stream>>>(xsb, Bb, Cb, dtsp, dta, Dv, hbase,
                                                   xsb /*Y in place*/, states, cs63);
    scan_k   <<<dim3(HG, B_, 8), 256, 0, stream>>>(states, cs63, hbase);
    yoff_k   <<<dim3(HG, NC, B_), 256, 0, stream>>>(Cb, states, dta, hbase, xsb /*Y*/);
  }
  gate_k<<<BL, 256, 0, stream>>>(xsb /*Y*/, zbuf, rms_w, yb);
  gemm_out_k<<<dim3(DM / 128, BL / 128), 256, 0, stream>>>(yb, W_out_b, out, x);
}